// Round 2
// baseline (17725.629 us; speedup 1.0000x reference)
//
#include <hip/hip_runtime.h>
#include <hip/hip_bf16.h>
#include <math.h>

#define Dm   1024
#define Hh   16
#define DHd  64
#define Sx   2048

__device__ __forceinline__ float dot4(float4 a, float4 b) {
    return a.x * b.x + a.y * b.y + a.z * b.z + a.w * b.w;
}
__device__ __forceinline__ float wave_sum64(float v) {
#pragma unroll
    for (int o = 32; o > 0; o >>= 1) v += __shfl_xor(v, o, 64);
    return v;
}

// ---------------------------------------------------------------- LayerNorm
__global__ __launch_bounds__(256) void ln_kernel(const float* __restrict__ x,
                                                 const float* __restrict__ g,
                                                 const float* __restrict__ b,
                                                 float* __restrict__ out) {
    int row = blockIdx.x;
    int tid = threadIdx.x;
    const float4* xr = (const float4*)(x + (size_t)row * Dm);
    float4 v = xr[tid];
    float s  = v.x + v.y + v.z + v.w;
    float ss = v.x * v.x + v.y * v.y + v.z * v.z + v.w * v.w;
    __shared__ float rbuf[8];
    s  = wave_sum64(s);
    ss = wave_sum64(ss);
    if ((tid & 63) == 0) { rbuf[tid >> 6] = s; rbuf[4 + (tid >> 6)] = ss; }
    __syncthreads();
    float mean = (rbuf[0] + rbuf[1] + rbuf[2] + rbuf[3]) * (1.0f / Dm);
    float msq  = (rbuf[4] + rbuf[5] + rbuf[6] + rbuf[7]) * (1.0f / Dm);
    float var  = msq - mean * mean;
    float rstd = 1.0f / sqrtf(var + 1e-5f);
    float4 gg = ((const float4*)g)[tid];
    float4 bb = ((const float4*)b)[tid];
    float4 o;
    o.x = (v.x - mean) * rstd * gg.x + bb.x;
    o.y = (v.y - mean) * rstd * gg.y + bb.y;
    o.z = (v.z - mean) * rstd * gg.z + bb.z;
    o.w = (v.w - mean) * rstd * gg.w + bb.w;
    ((float4*)(out + (size_t)row * Dm))[tid] = o;
}

// ---------------------------------------------------------------- sinusoidal PE
__global__ __launch_bounds__(256) void pe_kernel(float* __restrict__ pe) {
    int idx = blockIdx.x * 256 + threadIdx.x;
    int r = idx >> 9;
    int t = idx & 511;
    double div = exp((double)(2 * t) * (-9.210340371976184 / 1024.0));
    double ang = (double)r * div;
    pe[(size_t)r * Dm + 2 * t]     = (float)sin(ang);
    pe[(size_t)r * Dm + 2 * t + 1] = (float)cos(ang);
}

// ---------------------------------------------------------------- SGEMM 64x64, BK=32, 4x4/thread
__global__ __launch_bounds__(256) void sgemm64(const float* __restrict__ A,
                                               const float* __restrict__ B,
                                               const float* __restrict__ bias,
                                               float* __restrict__ C,
                                               int M, int N, int K) {
    __shared__ float As[32][68];
    __shared__ float Bs[32][68];
    int tid = threadIdx.x;
    int bn = blockIdx.x * 64, bm = blockIdx.y * 64;
    int am = tid >> 2, ak = (tid & 3) * 8;
    int bk = tid >> 3, bn8 = (tid & 7) * 8;
    int tm = tid >> 4, tn = tid & 15;
    float acc[4][4] = {};
    const float* Ap = A + (size_t)(bm + am) * K + ak;
    const float* Bp = B + (size_t)bk * N + bn + bn8;
    for (int k0 = 0; k0 < K; k0 += 32) {
        float4 a0 = *(const float4*)(Ap + k0);
        float4 a1 = *(const float4*)(Ap + k0 + 4);
        float4 b0 = *(const float4*)(Bp + (size_t)k0 * N);
        float4 b1 = *(const float4*)(Bp + (size_t)k0 * N + 4);
        __syncthreads();
        As[ak + 0][am] = a0.x; As[ak + 1][am] = a0.y;
        As[ak + 2][am] = a0.z; As[ak + 3][am] = a0.w;
        As[ak + 4][am] = a1.x; As[ak + 5][am] = a1.y;
        As[ak + 6][am] = a1.z; As[ak + 7][am] = a1.w;
        *(float4*)&Bs[bk][bn8]     = b0;
        *(float4*)&Bs[bk][bn8 + 4] = b1;
        __syncthreads();
#pragma unroll
        for (int kk = 0; kk < 32; kk++) {
            float4 a4 = *(const float4*)&As[kk][tm * 4];
            float4 b4 = *(const float4*)&Bs[kk][tn * 4];
            acc[0][0] += a4.x * b4.x; acc[0][1] += a4.x * b4.y; acc[0][2] += a4.x * b4.z; acc[0][3] += a4.x * b4.w;
            acc[1][0] += a4.y * b4.x; acc[1][1] += a4.y * b4.y; acc[1][2] += a4.y * b4.z; acc[1][3] += a4.y * b4.w;
            acc[2][0] += a4.z * b4.x; acc[2][1] += a4.z * b4.y; acc[2][2] += a4.z * b4.z; acc[2][3] += a4.z * b4.w;
            acc[3][0] += a4.w * b4.x; acc[3][1] += a4.w * b4.y; acc[3][2] += a4.w * b4.z; acc[3][3] += a4.w * b4.w;
        }
    }
    float bvr[4];
#pragma unroll
    for (int s = 0; s < 4; s++) bvr[s] = bias ? bias[bn + tn * 4 + s] : 0.0f;
#pragma unroll
    for (int r = 0; r < 4; r++) {
        float* cr = C + (size_t)(bm + tm * 4 + r) * N + bn + tn * 4;
        float4 o = { acc[r][0] + bvr[0], acc[r][1] + bvr[1], acc[r][2] + bvr[2], acc[r][3] + bvr[3] };
        *(float4*)cr = o;
    }
}

// ---------------------------------------------------------------- precompute u.k_j and vb.p_r
__global__ __launch_bounds__(256) void ukvb_kernel(const float* __restrict__ k,
                                                   const float* __restrict__ pp,
                                                   const float* __restrict__ u,
                                                   const float* __restrict__ vb,
                                                   float* __restrict__ ukg,
                                                   float* __restrict__ vbg) {
    int jid = blockIdx.x * 256 + threadIdx.x;
    if (jid < 2 * Hh * Sx) {
        int j = jid & 2047, h = (jid >> 11) & 15, b = jid >> 15;
        const float* kr = k + ((size_t)(b * Sx + j)) * Dm + h * 64;
        const float* ur = u + h * 64;
        float s = 0.0f;
#pragma unroll
        for (int d4 = 0; d4 < 16; d4++)
            s += dot4(*(const float4*)(kr + d4 * 4), *(const float4*)(ur + d4 * 4));
        ukg[jid] = s;
    } else {
        int jid2 = jid - 2 * Hh * Sx;   // < 16*2048
        int r = jid2 & 2047, h = jid2 >> 11;
        const float* pr = pp + (size_t)r * Dm + h * 64;
        const float* vr = vb + h * 64;
        float s = 0.0f;
#pragma unroll
        for (int d4 = 0; d4 < 16; d4++)
            s += dot4(*(const float4*)(pr + d4 * 4), *(const float4*)(vr + d4 * 4));
        vbg[jid2] = s;
    }
}

// ---------------------------------------------------------------- flash attention w/ rolling pos window
// block = (b, h, 64-query i-tile); j-tiles of 32.
// Virtual pos index v = S-1 + j - i:  v<S -> raw[i,v]; v==S -> 0; v>S -> raw[i+1, v-S-1].
// W window: rows il (64), 96 live columns of vr = v - a0 (a0 = 1984 - i0), circular mod 96.
__global__ __launch_bounds__(256) void flash_kernel(const float* __restrict__ q,
                                                    const float* __restrict__ k,
                                                    const float* __restrict__ v,
                                                    const float* __restrict__ pp,
                                                    const float* __restrict__ ukg,
                                                    const float* __restrict__ vbg,
                                                    float* __restrict__ head) {
    __shared__ float Qs[65][68];        // 17,680 B
    __shared__ float KP[64 * 36];       //  9,216 B: K-tile [32][68] union probs [64][36]
    __shared__ float PV[32][68];        //  8,704 B: Ps-tile / V-tile
    __shared__ float Ws[64 * 100];      // 25,600 B: rolling window, 96 cols used

    int tid = threadIdx.x;
    int blk = blockIdx.x;
    int it = blk & 31, h = (blk >> 5) & 15, b = blk >> 9;
    int i0 = it * 64;
    int a0 = 1984 - i0;

    const float* qb  = q  + ((size_t)b * Sx) * Dm + h * 64;
    const float* kb  = k  + ((size_t)b * Sx) * Dm + h * 64;
    const float* vb2 = v  + ((size_t)b * Sx) * Dm + h * 64;
    const float* ppb = pp + h * 64;
    const float* ukb = ukg + (size_t)(b * Hh + h) * Sx;
    const float* vbb = vbg + (size_t)h * Sx;

    // stage Q (65 rows; row 64 zero-padded at the last i-tile)
    for (int c = tid; c < 65 * 16; c += 256) {
        int row = c >> 4, d4 = c & 15;
        float4 val = {0, 0, 0, 0};
        int i = i0 + row;
        if (i < Sx) val = *(const float4*)(qb + (size_t)i * Dm + d4 * 4);
        *(float4*)&Qs[row][d4 * 4] = val;
    }

    int ti = tid >> 4, tj = tid & 15;
    int il0 = ti * 4;

    // ---- prologue: fill W for vr in [0, 95]  (3 phases of 32)
    for (int f = 0; f < 3; f++) {
        int vrb = f * 32;
        __syncthreads();
        for (int c = tid; c < 512; c += 256) {
            int vn = c >> 4, d4 = c & 15;
            int vv = a0 + vrb + vn;
            float4 val = {0, 0, 0, 0};
            if (vv != Sx) {
                int pc = vv < Sx ? vv : vv - Sx - 1;
                val = *(const float4*)(ppb + (size_t)pc * Dm + d4 * 4);
            }
            *(float4*)&PV[vn][d4 * 4] = val;
        }
        __syncthreads();
        {
            float wn[4][2] = {};
            const float* qrow[4][2];
            float vbv[2]; int vz[2]; int slot[2];
#pragma unroll
            for (int c = 0; c < 2; c++) {
                int vn = c * 16 + tj;
                int vv = a0 + vrb + vn;
                int off = vv > Sx ? 1 : 0;
                vz[c] = (vv == Sx);
                int pc = vv < Sx ? vv : vv - Sx - 1;
                vbv[c] = vz[c] ? 0.0f : vbb[pc];
                slot[c] = (vrb + vn) % 96;
#pragma unroll
                for (int r = 0; r < 4; r++) qrow[r][c] = &Qs[il0 + r + off][0];
            }
#pragma unroll
            for (int d4 = 0; d4 < 16; d4++) {
                float4 ps0 = *(const float4*)&PV[tj][d4 * 4];
                float4 ps1 = *(const float4*)&PV[16 + tj][d4 * 4];
#pragma unroll
                for (int r = 0; r < 4; r++) {
                    float4 qa = *(const float4*)(qrow[r][0] + d4 * 4);
                    float4 qc = *(const float4*)(qrow[r][1] + d4 * 4);
                    wn[r][0] += dot4(qa, ps0);
                    wn[r][1] += dot4(qc, ps1);
                }
            }
#pragma unroll
            for (int r = 0; r < 4; r++)
#pragma unroll
                for (int c = 0; c < 2; c++)
                    Ws[(il0 + r) * 100 + slot[c]] = vz[c] ? 0.0f : (wn[r][c] + vbv[c]);
        }
    }

    float O[4][4] = {};
    float m_i[4] = {-1e30f, -1e30f, -1e30f, -1e30f};
    float l_i[4] = {};
    float* Kt = KP;   // [32][68] view
    float* Pl = KP;   // [64][36] view

    int rv = tid >> 3, n8 = (tid & 7) * 8;

    for (int t = 0; t < 64; t++) {
        int j0 = t * 32;
        __syncthreads();   // B0: prior AV done
        // stage K; hold V in regs; stage Ps fill (t>=1)
        float4 kv0 = *(const float4*)(kb + (size_t)(j0 + rv) * Dm + n8);
        float4 kv1 = *(const float4*)(kb + (size_t)(j0 + rv) * Dm + n8 + 4);
        float4 vh0 = *(const float4*)(vb2 + (size_t)(j0 + rv) * Dm + n8);
        float4 vh1 = *(const float4*)(vb2 + (size_t)(j0 + rv) * Dm + n8 + 4);
        *(float4*)&Kt[rv * 68 + n8]     = kv0;
        *(float4*)&Kt[rv * 68 + n8 + 4] = kv1;
        int vrb = (t + 2) * 32;
        if (t >= 1) {
            for (int c = tid; c < 512; c += 256) {
                int vn = c >> 4, d4 = c & 15;
                int vv = a0 + vrb + vn;
                float4 val = {0, 0, 0, 0};
                if (vv != Sx) {
                    int pc = vv < Sx ? vv : vv - Sx - 1;
                    val = *(const float4*)(ppb + (size_t)pc * Dm + d4 * 4);
                }
                *(float4*)&PV[vn][d4 * 4] = val;
            }
        }
        float uk0 = ukb[j0 + tj];
        float uk1 = ukb[j0 + 16 + tj];
        __syncthreads();   // B1: K/Ps staged
        // content scores
        float s[4][2] = {};
#pragma unroll
        for (int d4 = 0; d4 < 16; d4++) {
            float4 k40 = *(const float4*)&Kt[tj * 68 + d4 * 4];
            float4 k41 = *(const float4*)&Kt[(16 + tj) * 68 + d4 * 4];
#pragma unroll
            for (int r = 0; r < 4; r++) {
                float4 q4 = *(const float4*)&Qs[il0 + r][d4 * 4];
                s[r][0] += dot4(q4, k40);
                s[r][1] += dot4(q4, k41);
            }
        }
        // W_new for fill f = t+2
        if (t >= 1) {
            float wn[4][2] = {};
            const float* qrow[4][2];
            float vbv[2]; int vz[2]; int slot[2];
#pragma unroll
            for (int c = 0; c < 2; c++) {
                int vn = c * 16 + tj;
                int vv = a0 + vrb + vn;
                int off = vv > Sx ? 1 : 0;
                vz[c] = (vv == Sx);
                int pc = vv < Sx ? vv : vv - Sx - 1;
                vbv[c] = vz[c] ? 0.0f : vbb[pc];
                slot[c] = (vrb + vn) % 96;
#pragma unroll
                for (int r = 0; r < 4; r++) qrow[r][c] = &Qs[il0 + r + off][0];
            }
#pragma unroll
            for (int d4 = 0; d4 < 16; d4++) {
                float4 ps0 = *(const float4*)&PV[tj][d4 * 4];
                float4 ps1 = *(const float4*)&PV[16 + tj][d4 * 4];
#pragma unroll
                for (int r = 0; r < 4; r++) {
                    float4 qa = *(const float4*)(qrow[r][0] + d4 * 4);
                    float4 qc = *(const float4*)(qrow[r][1] + d4 * 4);
                    wn[r][0] += dot4(qa, ps0);
                    wn[r][1] += dot4(qc, ps1);
                }
            }
#pragma unroll
            for (int r = 0; r < 4; r++)
#pragma unroll
                for (int c = 0; c < 2; c++)
                    Ws[(il0 + r) * 100 + slot[c]] = vz[c] ? 0.0f : (wn[r][c] + vbv[c]);
        }
        __syncthreads();   // B2: W visible; K/Ps dead
        // V regs -> LDS (overwrites Ps)
        *(float4*)&PV[rv][n8]     = vh0;
        *(float4*)&PV[rv][n8 + 4] = vh1;
        // combine + online softmax
        float p[4][2]; float alpha[4];
#pragma unroll
        for (int r = 0; r < 4; r++) {
            int il = il0 + r;
            float pos0 = Ws[il * 100 + (63 + j0 + tj - il) % 96];
            float pos1 = Ws[il * 100 + (79 + j0 + tj - il) % 96];
            float lg0 = (s[r][0] + uk0 + pos0) * 0.125f;
            float lg1 = (s[r][1] + uk1 + pos1) * 0.125f;
            float mx = fmaxf(lg0, lg1);
#pragma unroll
            for (int o = 1; o < 16; o <<= 1) mx = fmaxf(mx, __shfl_xor(mx, o, 64));
            float mn = fmaxf(m_i[r], mx);
            alpha[r] = expf(m_i[r] - mn);
            float p0 = expf(lg0 - mn), p1 = expf(lg1 - mn);
            float ls = p0 + p1;
#pragma unroll
            for (int o = 1; o < 16; o <<= 1) ls += __shfl_xor(ls, o, 64);
            l_i[r] = l_i[r] * alpha[r] + ls;
            m_i[r] = mn;
            p[r][0] = p0; p[r][1] = p1;
        }
#pragma unroll
        for (int r = 0; r < 4; r++) {
            int il = il0 + r;
            Pl[il * 36 + tj]      = p[r][0];
            Pl[il * 36 + 16 + tj] = p[r][1];
#pragma unroll
            for (int sd = 0; sd < 4; sd++) O[r][sd] *= alpha[r];
        }
        __syncthreads();   // B3: probs + V staged
        // O += P . V
#pragma unroll
        for (int j4 = 0; j4 < 8; j4++) {
            float4 v40 = *(const float4*)&PV[j4 * 4 + 0][tj * 4];
            float4 v41 = *(const float4*)&PV[j4 * 4 + 1][tj * 4];
            float4 v42 = *(const float4*)&PV[j4 * 4 + 2][tj * 4];
            float4 v43 = *(const float4*)&PV[j4 * 4 + 3][tj * 4];
#pragma unroll
            for (int r = 0; r < 4; r++) {
                float4 p4 = *(const float4*)&Pl[(il0 + r) * 36 + j4 * 4];
                O[r][0] += p4.x * v40.x + p4.y * v41.x + p4.z * v42.x + p4.w * v43.x;
                O[r][1] += p4.x * v40.y + p4.y * v41.y + p4.z * v42.y + p4.w * v43.y;
                O[r][2] += p4.x * v40.z + p4.y * v41.z + p4.z * v42.z + p4.w * v43.z;
                O[r][3] += p4.x * v40.w + p4.y * v41.w + p4.z * v42.w + p4.w * v43.w;
            }
        }
    }
#pragma unroll
    for (int r = 0; r < 4; r++) {
        float inv = 1.0f / l_i[r];
        float4 o4 = { O[r][0] * inv, O[r][1] * inv, O[r][2] * inv, O[r][3] * inv };
        *(float4*)(head + ((size_t)(b * Sx + i0 + il0 + r)) * Dm + h * 64 + tj * 4) = o4;
    }
}

// ---------------------------------------------------------------- launcher
extern "C" void kernel_launch(void* const* d_in, const int* in_sizes, int n_in,
                              void* d_out, int out_size, void* d_ws, size_t ws_size,
                              hipStream_t stream) {
    const float* x    = (const float*)d_in[0];
    const float* ln_g = (const float*)d_in[1];
    const float* ln_b = (const float*)d_in[2];
    const float* Wq   = (const float*)d_in[3];
    const float* bq   = (const float*)d_in[4];
    const float* Wk   = (const float*)d_in[5];
    const float* bk   = (const float*)d_in[6];
    const float* Wv   = (const float*)d_in[7];
    const float* bv   = (const float*)d_in[8];
    const float* Wp   = (const float*)d_in[9];
    const float* Wo   = (const float*)d_in[10];
    const float* bo   = (const float*)d_in[11];
    const float* ub   = (const float*)d_in[12];
    const float* vbias= (const float*)d_in[13];

    float* out = (float*)d_out;
    float* ws  = (float*)d_ws;

    const int MROWS = 2 * Sx;                     // 4096
    float* xn   = out;                            // alias; final GEMM rewrites out
    float* qbuf = ws;                             // 4M floats
    float* kbuf = ws + 4u  * 1024 * 1024;
    float* vbuf = ws + 8u  * 1024 * 1024;
    float* pe   = ws + 12u * 1024 * 1024;         // 2M (reused for ukg/vbg after pp GEMM)
    float* pp   = ws + 14u * 1024 * 1024;         // 2M
    float* head = ws + 16u * 1024 * 1024;         // 4M  -> 80MB total
    float* ukg  = pe;                             // 65536 floats (pe dead after pp GEMM)
    float* vbg  = pe + 2 * Hh * Sx;               // 32768 floats

    ln_kernel<<<MROWS, 256, 0, stream>>>(x, ln_g, ln_b, xn);
    pe_kernel<<<Sx * 512 / 256, 256, 0, stream>>>(pe);

    dim3 g1(Dm / 64, MROWS / 64);                 // (16, 64)
    sgemm64<<<g1, 256, 0, stream>>>(xn, Wq, bq, qbuf, MROWS, Dm, Dm);
    sgemm64<<<g1, 256, 0, stream>>>(xn, Wk, bk, kbuf, MROWS, Dm, Dm);
    sgemm64<<<g1, 256, 0, stream>>>(xn, Wv, bv, vbuf, MROWS, Dm, Dm);
    dim3 g2(Dm / 64, Sx / 64);                    // (16, 32)
    sgemm64<<<g2, 256, 0, stream>>>(pe, Wp, nullptr, pp, Sx, Dm, Dm);

    ukvb_kernel<<<(2 * Hh * Sx + Hh * Sx) / 256, 256, 0, stream>>>(kbuf, pp, ub, vbias, ukg, vbg);

    flash_kernel<<<2 * Hh * 32, 256, 0, stream>>>(qbuf, kbuf, vbuf, pp, ukg, vbg, head);

    sgemm64<<<g1, 256, 0, stream>>>(head, Wo, bo, out, MROWS, Dm, Dm);
}

// Round 3
// 1907.086 us; speedup vs baseline: 9.2946x; 9.2946x over previous
//
#include <hip/hip_runtime.h>
#include <hip/hip_bf16.h>
#include <math.h>

#define Dm   1024
#define Hh   16
#define Sx   2048
#define WCOL 97          // Ws row stride (96 circular columns used)

__device__ __forceinline__ float dot4(float4 a, float4 b) {
    return a.x * b.x + a.y * b.y + a.z * b.z + a.w * b.w;
}
__device__ __forceinline__ float wave_sum64(float v) {
#pragma unroll
    for (int o = 32; o > 0; o >>= 1) v += __shfl_xor(v, o, 64);
    return v;
}

// ---------------------------------------------------------------- LayerNorm
__global__ __launch_bounds__(256) void ln_kernel(const float* __restrict__ x,
                                                 const float* __restrict__ g,
                                                 const float* __restrict__ b,
                                                 float* __restrict__ out) {
    int row = blockIdx.x;
    int tid = threadIdx.x;
    const float4* xr = (const float4*)(x + (size_t)row * Dm);
    float4 v = xr[tid];
    float s  = v.x + v.y + v.z + v.w;
    float ss = v.x * v.x + v.y * v.y + v.z * v.z + v.w * v.w;
    __shared__ float rbuf[8];
    s  = wave_sum64(s);
    ss = wave_sum64(ss);
    if ((tid & 63) == 0) { rbuf[tid >> 6] = s; rbuf[4 + (tid >> 6)] = ss; }
    __syncthreads();
    float mean = (rbuf[0] + rbuf[1] + rbuf[2] + rbuf[3]) * (1.0f / Dm);
    float msq  = (rbuf[4] + rbuf[5] + rbuf[6] + rbuf[7]) * (1.0f / Dm);
    float var  = msq - mean * mean;
    float rstd = 1.0f / sqrtf(var + 1e-5f);
    float4 gg = ((const float4*)g)[tid];
    float4 bb = ((const float4*)b)[tid];
    float4 o;
    o.x = (v.x - mean) * rstd * gg.x + bb.x;
    o.y = (v.y - mean) * rstd * gg.y + bb.y;
    o.z = (v.z - mean) * rstd * gg.z + bb.z;
    o.w = (v.w - mean) * rstd * gg.w + bb.w;
    ((float4*)(out + (size_t)row * Dm))[tid] = o;
}

// ---------------------------------------------------------------- sinusoidal PE
__global__ __launch_bounds__(256) void pe_kernel(float* __restrict__ pe) {
    int idx = blockIdx.x * 256 + threadIdx.x;
    int r = idx >> 9;
    int t = idx & 511;
    double div = exp((double)(2 * t) * (-9.210340371976184 / 1024.0));
    double ang = (double)r * div;
    pe[(size_t)r * Dm + 2 * t]     = (float)sin(ang);
    pe[(size_t)r * Dm + 2 * t + 1] = (float)cos(ang);
}

// ---------------------------------------------------------------- SGEMM 64x64, BK=32, 4x4/thread
__global__ __launch_bounds__(256) void sgemm64(const float* __restrict__ A,
                                               const float* __restrict__ B,
                                               const float* __restrict__ bias,
                                               float* __restrict__ C,
                                               int M, int N, int K) {
    __shared__ float As[32][68];
    __shared__ float Bs[32][68];
    int tid = threadIdx.x;
    int bn = blockIdx.x * 64, bm = blockIdx.y * 64;
    int am = tid >> 2, ak = (tid & 3) * 8;
    int bk = tid >> 3, bn8 = (tid & 7) * 8;
    int tm = tid >> 4, tn = tid & 15;
    float acc[4][4] = {};
    const float* Ap = A + (size_t)(bm + am) * K + ak;
    const float* Bp = B + (size_t)bk * N + bn + bn8;
    for (int k0 = 0; k0 < K; k0 += 32) {
        float4 a0 = *(const float4*)(Ap + k0);
        float4 a1 = *(const float4*)(Ap + k0 + 4);
        float4 b0 = *(const float4*)(Bp + (size_t)k0 * N);
        float4 b1 = *(const float4*)(Bp + (size_t)k0 * N + 4);
        __syncthreads();
        As[ak + 0][am] = a0.x; As[ak + 1][am] = a0.y;
        As[ak + 2][am] = a0.z; As[ak + 3][am] = a0.w;
        As[ak + 4][am] = a1.x; As[ak + 5][am] = a1.y;
        As[ak + 6][am] = a1.z; As[ak + 7][am] = a1.w;
        *(float4*)&Bs[bk][bn8]     = b0;
        *(float4*)&Bs[bk][bn8 + 4] = b1;
        __syncthreads();
#pragma unroll
        for (int kk = 0; kk < 32; kk++) {
            float4 a4 = *(const float4*)&As[kk][tm * 4];
            float4 b4 = *(const float4*)&Bs[kk][tn * 4];
            acc[0][0] += a4.x * b4.x; acc[0][1] += a4.x * b4.y; acc[0][2] += a4.x * b4.z; acc[0][3] += a4.x * b4.w;
            acc[1][0] += a4.y * b4.x; acc[1][1] += a4.y * b4.y; acc[1][2] += a4.y * b4.z; acc[1][3] += a4.y * b4.w;
            acc[2][0] += a4.z * b4.x; acc[2][1] += a4.z * b4.y; acc[2][2] += a4.z * b4.z; acc[2][3] += a4.z * b4.w;
            acc[3][0] += a4.w * b4.x; acc[3][1] += a4.w * b4.y; acc[3][2] += a4.w * b4.z; acc[3][3] += a4.w * b4.w;
        }
    }
    float bvr[4];
#pragma unroll
    for (int s = 0; s < 4; s++) bvr[s] = bias ? bias[bn + tn * 4 + s] : 0.0f;
#pragma unroll
    for (int r = 0; r < 4; r++) {
        float* cr = C + (size_t)(bm + tm * 4 + r) * N + bn + tn * 4;
        float4 o = { acc[r][0] + bvr[0], acc[r][1] + bvr[1], acc[r][2] + bvr[2], acc[r][3] + bvr[3] };
        *(float4*)cr = o;
    }
}

// ---------------------------------------------------------------- precompute u.k_j and vb.p_r
__global__ __launch_bounds__(256) void ukvb_kernel(const float* __restrict__ k,
                                                   const float* __restrict__ pp,
                                                   const float* __restrict__ u,
                                                   const float* __restrict__ vb,
                                                   float* __restrict__ ukg,
                                                   float* __restrict__ vbg) {
    int jid = blockIdx.x * 256 + threadIdx.x;
    if (jid < 2 * Hh * Sx) {
        int j = jid & 2047, h = (jid >> 11) & 15;
        int b = jid >> 15;
        const float* kr = k + ((size_t)(b * Sx + j)) * Dm + h * 64;
        const float* ur = u + h * 64;
        float s = 0.0f;
#pragma unroll
        for (int d4 = 0; d4 < 16; d4++)
            s += dot4(*(const float4*)(kr + d4 * 4), *(const float4*)(ur + d4 * 4));
        ukg[jid] = s;
    } else {
        int jid2 = jid - 2 * Hh * Sx;
        int r = jid2 & 2047, h = jid2 >> 11;
        const float* pr = pp + (size_t)r * Dm + h * 64;
        const float* vr = vb + h * 64;
        float s = 0.0f;
#pragma unroll
        for (int d4 = 0; d4 < 16; d4++)
            s += dot4(*(const float4*)(pr + d4 * 4), *(const float4*)(vr + d4 * 4));
        vbg[jid2] = s;
    }
}

// ---------------------------------------------------------------- flash attention, low-pressure restructure
// block = (b, h, 64-query tile); j-tiles of 32; thread (ti=tid>>4, tj=tid&15):
// score rows r0=4*ti, cols {tj, tj+16}.  Window Ws[64 rows][96 circ]:
// row r0..r0+3 written & read ONLY by group ti (wave-local -> no barrier).
// v = S-1+j-i ; v<S -> (q_i+vb).p_v ; v==S -> 0 ; v>S -> (q_{i+1}+vb).p_{v-S-1}
__global__ __launch_bounds__(256) void flash_kernel(const float* __restrict__ q,
                                                    const float* __restrict__ k,
                                                    const float* __restrict__ v,
                                                    const float* __restrict__ pp,
                                                    const float* __restrict__ ukg,
                                                    const float* __restrict__ vbg,
                                                    float* __restrict__ head) {
    extern __shared__ float smem[];
    float* Qs  = smem;                 // [65][68]
    float* Kt  = Qs  + 65 * 68;        // [32][68]
    float* Vt  = Kt  + 32 * 68;        // [32][68]
    float* PW  = Vt  + 32 * 68;        // [32][68]  staged p-columns
    float* PlT = PW  + 32 * 68;        // [32][68]  probs, j-major
    float* Ws  = PlT + 32 * 68;        // [64][97]  rolling window

    int tid = threadIdx.x;
    int blk = blockIdx.x;
    int it = blk & 31, h = (blk >> 5) & 15, b = blk >> 9;
    int i0 = it * 64;
    int a0 = 1984 - i0;                // v offset: vr = v - a0

    const float* qb  = q   + ((size_t)b * Sx) * Dm + h * 64;
    const float* kb  = k   + ((size_t)b * Sx) * Dm + h * 64;
    const float* vb2 = v   + ((size_t)b * Sx) * Dm + h * 64;
    const float* ppb = pp  + h * 64;
    const float* ukb = ukg + (size_t)(b * Hh + h) * Sx;
    const float* vbb = vbg + (size_t)h * Sx;

    int ti = tid >> 4, tj = tid & 15;
    int r0 = ti * 4;
    int n0 = tj, n1 = tj + 16;
    int rv = tid >> 3, n8 = (tid & 7) * 8;

    // ---- stage Q rows i0..i0+64 (65 rows, zero-pad OOB)
    for (int c = tid; c < 65 * 16; c += 256) {
        int row = c >> 4, d4 = c & 15;
        float4 val = {0, 0, 0, 0};
        int i = i0 + row;
        if (i < Sx) val = *(const float4*)(qb + (size_t)i * Dm + d4 * 4);
        *(float4*)&Qs[row * 68 + d4 * 4] = val;
    }

    // ---- prologue: fill window vr in [0,96), 3 phases of 32
    for (int f = 0; f < 3; f++) {
        int vrb = f * 32;
        __syncthreads();
        {   // stage PW rows [0,32) for this phase
            int vv = a0 + vrb + rv;
            float4 z0 = {0, 0, 0, 0}, z1 = {0, 0, 0, 0};
            if (vv != Sx) {
                int pc = vv < Sx ? vv : vv - Sx - 1;
                const float* pr = ppb + (size_t)pc * Dm + n8;
                z0 = *(const float4*)pr;
                z1 = *(const float4*)(pr + 4);
            }
            *(float4*)&PW[rv * 68 + n8]     = z0;
            *(float4*)&PW[rv * 68 + n8 + 4] = z1;
        }
        __syncthreads();
        {   // W-fill (wave-local rows)
            int v0 = a0 + vrb + n0, v1 = a0 + vrb + n1;
            int off0 = v0 > Sx ? 1 : 0, off1 = v1 > Sx ? 1 : 0;
            bool z0 = (v0 == Sx), z1 = (v1 == Sx);
            int pc0 = v0 < Sx ? v0 : v0 - Sx - 1;
            int pc1 = v1 < Sx ? v1 : v1 - Sx - 1;
            float vbv0 = z0 ? 0.0f : vbb[pc0];
            float vbv1 = z1 ? 0.0f : vbb[pc1];
            float wn[4][2] = {};
            if (off0 == off1) {
                const float* qp = &Qs[(r0 + off0) * 68];
#pragma unroll 4
                for (int d4 = 0; d4 < 16; d4++) {
                    float4 p0 = *(const float4*)&PW[n0 * 68 + d4 * 4];
                    float4 p1 = *(const float4*)&PW[n1 * 68 + d4 * 4];
#pragma unroll
                    for (int r = 0; r < 4; r++) {
                        float4 qq = *(const float4*)(qp + r * 68 + d4 * 4);
                        wn[r][0] += dot4(qq, p0);
                        wn[r][1] += dot4(qq, p1);
                    }
                }
            } else {
                const float* qp0 = &Qs[(r0 + off0) * 68];
                const float* qp1 = &Qs[(r0 + off1) * 68];
#pragma unroll 4
                for (int d4 = 0; d4 < 16; d4++) {
                    float4 p0 = *(const float4*)&PW[n0 * 68 + d4 * 4];
                    float4 p1 = *(const float4*)&PW[n1 * 68 + d4 * 4];
#pragma unroll
                    for (int r = 0; r < 4; r++) {
                        float4 qa = *(const float4*)(qp0 + r * 68 + d4 * 4);
                        float4 qc = *(const float4*)(qp1 + r * 68 + d4 * 4);
                        wn[r][0] += dot4(qa, p0);
                        wn[r][1] += dot4(qc, p1);
                    }
                }
            }
            int s0 = (vrb + n0) % 96, s1 = (vrb + n1) % 96;
#pragma unroll
            for (int r = 0; r < 4; r++) {
                Ws[(r0 + r) * WCOL + s0] = z0 ? 0.0f : wn[r][0] + vbv0;
                Ws[(r0 + r) * WCOL + s1] = z1 ? 0.0f : wn[r][1] + vbv1;
            }
        }
    }

    float O[4][4] = {};
    float m_i[4] = {-1e30f, -1e30f, -1e30f, -1e30f};
    float l_i[4] = {};

    for (int t = 0; t < 64; t++) {
        int j0 = t * 32;
        __syncthreads();   // B0: prior AV / fill done; buffers free
        {   // stage K, V rows j0+rv; PW for vrb = j0+64 (t>=1)
            const float* krow = kb  + (size_t)(j0 + rv) * Dm + n8;
            const float* vrow = vb2 + (size_t)(j0 + rv) * Dm + n8;
            float4 k0 = *(const float4*)krow;
            float4 k1 = *(const float4*)(krow + 4);
            float4 v0 = *(const float4*)vrow;
            float4 v1 = *(const float4*)(vrow + 4);
            *(float4*)&Kt[rv * 68 + n8]     = k0;
            *(float4*)&Kt[rv * 68 + n8 + 4] = k1;
            *(float4*)&Vt[rv * 68 + n8]     = v0;
            *(float4*)&Vt[rv * 68 + n8 + 4] = v1;
            if (t >= 1) {
                int vv = a0 + j0 + 64 + rv;
                float4 z0 = {0, 0, 0, 0}, z1 = {0, 0, 0, 0};
                if (vv != Sx) {
                    int pc = vv < Sx ? vv : vv - Sx - 1;
                    const float* pr = ppb + (size_t)pc * Dm + n8;
                    z0 = *(const float4*)pr;
                    z1 = *(const float4*)(pr + 4);
                }
                *(float4*)&PW[rv * 68 + n8]     = z0;
                *(float4*)&PW[rv * 68 + n8 + 4] = z1;
            }
        }
        float uk0 = ukb[j0 + n0];
        float uk1 = ukb[j0 + n1];
        __syncthreads();   // B1: tiles staged

        // ---- content scores
        float s[4][2] = {};
#pragma unroll 4
        for (int d4 = 0; d4 < 16; d4++) {
            float4 k0 = *(const float4*)&Kt[n0 * 68 + d4 * 4];
            float4 k1 = *(const float4*)&Kt[n1 * 68 + d4 * 4];
#pragma unroll
            for (int r = 0; r < 4; r++) {
                float4 qq = *(const float4*)&Qs[(r0 + r) * 68 + d4 * 4];
                s[r][0] += dot4(qq, k0);
                s[r][1] += dot4(qq, k1);
            }
        }

        // ---- window fill for vr in [j0+64, j0+96)  (wave-local rows)
        if (t >= 1) {
            int vrb = j0 + 64;
            int v0 = a0 + vrb + n0, v1 = a0 + vrb + n1;
            int off0 = v0 > Sx ? 1 : 0, off1 = v1 > Sx ? 1 : 0;
            bool z0 = (v0 == Sx), z1 = (v1 == Sx);
            int pc0 = v0 < Sx ? v0 : v0 - Sx - 1;
            int pc1 = v1 < Sx ? v1 : v1 - Sx - 1;
            float vbv0 = z0 ? 0.0f : vbb[pc0];
            float vbv1 = z1 ? 0.0f : vbb[pc1];
            float wn[4][2] = {};
            if (off0 == off1) {
                const float* qp = &Qs[(r0 + off0) * 68];
#pragma unroll 4
                for (int d4 = 0; d4 < 16; d4++) {
                    float4 p0 = *(const float4*)&PW[n0 * 68 + d4 * 4];
                    float4 p1 = *(const float4*)&PW[n1 * 68 + d4 * 4];
#pragma unroll
                    for (int r = 0; r < 4; r++) {
                        float4 qq = *(const float4*)(qp + r * 68 + d4 * 4);
                        wn[r][0] += dot4(qq, p0);
                        wn[r][1] += dot4(qq, p1);
                    }
                }
            } else {
                const float* qp0 = &Qs[(r0 + off0) * 68];
                const float* qp1 = &Qs[(r0 + off1) * 68];
#pragma unroll 4
                for (int d4 = 0; d4 < 16; d4++) {
                    float4 p0 = *(const float4*)&PW[n0 * 68 + d4 * 4];
                    float4 p1 = *(const float4*)&PW[n1 * 68 + d4 * 4];
#pragma unroll
                    for (int r = 0; r < 4; r++) {
                        float4 qa = *(const float4*)(qp0 + r * 68 + d4 * 4);
                        float4 qc = *(const float4*)(qp1 + r * 68 + d4 * 4);
                        wn[r][0] += dot4(qa, p0);
                        wn[r][1] += dot4(qc, p1);
                    }
                }
            }
            int sl0 = (vrb + n0) % 96, sl1 = (vrb + n1) % 96;
#pragma unroll
            for (int r = 0; r < 4; r++) {
                Ws[(r0 + r) * WCOL + sl0] = z0 ? 0.0f : wn[r][0] + vbv0;
                Ws[(r0 + r) * WCOL + sl1] = z1 ? 0.0f : wn[r][1] + vbv1;
            }
        }

        // ---- combine + online softmax (window reads are wave-local)
        float pr0[4], pr1[4];
#pragma unroll
        for (int r = 0; r < 4; r++) {
            int row = r0 + r;
            float pos0 = Ws[row * WCOL + (63 + j0 + n0 - row) % 96];
            float pos1 = Ws[row * WCOL + (63 + j0 + n1 - row) % 96];
            float lg0 = (s[r][0] + uk0 + pos0) * 0.125f;
            float lg1 = (s[r][1] + uk1 + pos1) * 0.125f;
            float mx = fmaxf(lg0, lg1);
#pragma unroll
            for (int o = 1; o < 16; o <<= 1) mx = fmaxf(mx, __shfl_xor(mx, o, 64));
            float mn = fmaxf(m_i[r], mx);
            float alpha = __expf(m_i[r] - mn);
            float p0 = __expf(lg0 - mn), p1 = __expf(lg1 - mn);
            float ls = p0 + p1;
#pragma unroll
            for (int o = 1; o < 16; o <<= 1) ls += __shfl_xor(ls, o, 64);
            l_i[r] = l_i[r] * alpha + ls;
            m_i[r] = mn;
            pr0[r] = p0; pr1[r] = p1;
#pragma unroll
            for (int d = 0; d < 4; d++) O[r][d] *= alpha;
        }
        // probs -> PlT (j-major; wave-local consumption)
        *(float4*)&PlT[n0 * 68 + r0] = *(float4*)pr0;
        *(float4*)&PlT[n1 * 68 + r0] = *(float4*)pr1;

        // ---- O += P.V
#pragma unroll 4
        for (int j = 0; j < 32; j++) {
            float4 pv = *(const float4*)&PlT[j * 68 + r0];
            float4 vv = *(const float4*)&Vt[j * 68 + tj * 4];
            O[0][0] += pv.x * vv.x; O[0][1] += pv.x * vv.y; O[0][2] += pv.x * vv.z; O[0][3] += pv.x * vv.w;
            O[1][0] += pv.y * vv.x; O[1][1] += pv.y * vv.y; O[1][2] += pv.y * vv.z; O[1][3] += pv.y * vv.w;
            O[2][0] += pv.z * vv.x; O[2][1] += pv.z * vv.y; O[2][2] += pv.z * vv.z; O[2][3] += pv.z * vv.w;
            O[3][0] += pv.w * vv.x; O[3][1] += pv.w * vv.y; O[3][2] += pv.w * vv.z; O[3][3] += pv.w * vv.w;
        }
    }

#pragma unroll
    for (int r = 0; r < 4; r++) {
        float inv = 1.0f / l_i[r];
        float4 o4 = { O[r][0] * inv, O[r][1] * inv, O[r][2] * inv, O[r][3] * inv };
        *(float4*)(head + ((size_t)(b * Sx + i0 + r0 + r)) * Dm + h * 64 + tj * 4) = o4;
    }
}

// ---------------------------------------------------------------- launcher
extern "C" void kernel_launch(void* const* d_in, const int* in_sizes, int n_in,
                              void* d_out, int out_size, void* d_ws, size_t ws_size,
                              hipStream_t stream) {
    const float* x    = (const float*)d_in[0];
    const float* ln_g = (const float*)d_in[1];
    const float* ln_b = (const float*)d_in[2];
    const float* Wq   = (const float*)d_in[3];
    const float* bq   = (const float*)d_in[4];
    const float* Wk   = (const float*)d_in[5];
    const float* bk   = (const float*)d_in[6];
    const float* Wv   = (const float*)d_in[7];
    const float* bv   = (const float*)d_in[8];
    const float* Wp   = (const float*)d_in[9];
    const float* Wo   = (const float*)d_in[10];
    const float* bo   = (const float*)d_in[11];
    const float* ub   = (const float*)d_in[12];
    const float* vbias= (const float*)d_in[13];

    float* out = (float*)d_out;
    float* ws  = (float*)d_ws;

    const int MROWS = 2 * Sx;                     // 4096
    float* xn   = out;                            // alias; final GEMM rewrites out
    float* qbuf = ws;
    float* kbuf = ws + 4u  * 1024 * 1024;
    float* vbuf = ws + 8u  * 1024 * 1024;
    float* pe   = ws + 12u * 1024 * 1024;         // reused as ukg/vbg after pp GEMM
    float* pp   = ws + 14u * 1024 * 1024;
    float* head = ws + 16u * 1024 * 1024;
    float* ukg  = pe;
    float* vbg  = pe + 2 * Hh * Sx;

    const int SHBYTES = (65 * 68 + 4 * 32 * 68 + 64 * WCOL) * 4;   // 77,328 B
    hipFuncSetAttribute(reinterpret_cast<const void*>(flash_kernel),
                        hipFuncAttributeMaxDynamicSharedMemorySize, SHBYTES);

    ln_kernel<<<MROWS, 256, 0, stream>>>(x, ln_g, ln_b, xn);
    pe_kernel<<<Sx * 512 / 256, 256, 0, stream>>>(pe);

    dim3 g1(Dm / 64, MROWS / 64);
    sgemm64<<<g1, 256, 0, stream>>>(xn, Wq, bq, qbuf, MROWS, Dm, Dm);
    sgemm64<<<g1, 256, 0, stream>>>(xn, Wk, bk, kbuf, MROWS, Dm, Dm);
    sgemm64<<<g1, 256, 0, stream>>>(xn, Wv, bv, vbuf, MROWS, Dm, Dm);
    dim3 g2(Dm / 64, Sx / 64);
    sgemm64<<<g2, 256, 0, stream>>>(pe, Wp, nullptr, pp, Sx, Dm, Dm);

    ukvb_kernel<<<(2 * Hh * Sx + Hh * Sx) / 256, 256, 0, stream>>>(kbuf, pp, ub, vbias, ukg, vbg);

    flash_kernel<<<2 * Hh * 32, 256, SHBYTES, stream>>>(qbuf, kbuf, vbuf, pp, ukg, vbg, head);

    sgemm64<<<g1, 256, 0, stream>>>(head, Wo, bo, out, MROWS, Dm, Dm);
}

// Round 4
// 1063.470 us; speedup vs baseline: 16.6677x; 1.7933x over previous
//
#include <hip/hip_runtime.h>
#include <hip/hip_bf16.h>
#include <math.h>

#define Dm   1024
#define Hh   16
#define Sx   2048

typedef short s16x8 __attribute__((ext_vector_type(8)));
typedef float f32x4 __attribute__((ext_vector_type(4)));

__device__ __forceinline__ float dot4(float4 a, float4 b) {
    return a.x * b.x + a.y * b.y + a.z * b.z + a.w * b.w;
}
__device__ __forceinline__ float wave_sum64(float v) {
#pragma unroll
    for (int o = 32; o > 0; o >>= 1) v += __shfl_xor(v, o, 64);
    return v;
}
__device__ __forceinline__ unsigned short f2bf(float x) {
    unsigned int u = __float_as_uint(x);
    unsigned int r = u + 0x7FFFu + ((u >> 16) & 1u);
    return (unsigned short)(r >> 16);
}
__device__ __forceinline__ s16x8 cvt8(const float* src) {
    float4 f0 = *(const float4*)src;
    float4 f1 = *(const float4*)(src + 4);
    s16x8 t;
    t[0] = (short)f2bf(f0.x); t[1] = (short)f2bf(f0.y);
    t[2] = (short)f2bf(f0.z); t[3] = (short)f2bf(f0.w);
    t[4] = (short)f2bf(f1.x); t[5] = (short)f2bf(f1.y);
    t[6] = (short)f2bf(f1.z); t[7] = (short)f2bf(f1.w);
    return t;
}

// ---------------------------------------------------------------- LayerNorm
__global__ __launch_bounds__(256) void ln_kernel(const float* __restrict__ x,
                                                 const float* __restrict__ g,
                                                 const float* __restrict__ b,
                                                 float* __restrict__ out) {
    int row = blockIdx.x;
    int tid = threadIdx.x;
    const float4* xr = (const float4*)(x + (size_t)row * Dm);
    float4 v = xr[tid];
    float s  = v.x + v.y + v.z + v.w;
    float ss = v.x * v.x + v.y * v.y + v.z * v.z + v.w * v.w;
    __shared__ float rbuf[8];
    s  = wave_sum64(s);
    ss = wave_sum64(ss);
    if ((tid & 63) == 0) { rbuf[tid >> 6] = s; rbuf[4 + (tid >> 6)] = ss; }
    __syncthreads();
    float mean = (rbuf[0] + rbuf[1] + rbuf[2] + rbuf[3]) * (1.0f / Dm);
    float msq  = (rbuf[4] + rbuf[5] + rbuf[6] + rbuf[7]) * (1.0f / Dm);
    float var  = msq - mean * mean;
    float rstd = 1.0f / sqrtf(var + 1e-5f);
    float4 gg = ((const float4*)g)[tid];
    float4 bb = ((const float4*)b)[tid];
    float4 o;
    o.x = (v.x - mean) * rstd * gg.x + bb.x;
    o.y = (v.y - mean) * rstd * gg.y + bb.y;
    o.z = (v.z - mean) * rstd * gg.z + bb.z;
    o.w = (v.w - mean) * rstd * gg.w + bb.w;
    ((float4*)(out + (size_t)row * Dm))[tid] = o;
}

// ---------------------------------------------------------------- sinusoidal PE
__global__ __launch_bounds__(256) void pe_kernel(float* __restrict__ pe) {
    int idx = blockIdx.x * 256 + threadIdx.x;
    int r = idx >> 9;
    int t = idx & 511;
    double div = exp((double)(2 * t) * (-9.210340371976184 / 1024.0));
    double ang = (double)r * div;
    pe[(size_t)r * Dm + 2 * t]     = (float)sin(ang);
    pe[(size_t)r * Dm + 2 * t + 1] = (float)cos(ang);
}

// ---------------------------------------------------------------- SGEMM 64x64, BK=32, 4x4/thread
__global__ __launch_bounds__(256) void sgemm64(const float* __restrict__ A,
                                               const float* __restrict__ B,
                                               const float* __restrict__ bias,
                                               float* __restrict__ C,
                                               int M, int N, int K) {
    __shared__ float As[32][68];
    __shared__ float Bs[32][68];
    int tid = threadIdx.x;
    int bn = blockIdx.x * 64, bm = blockIdx.y * 64;
    int am = tid >> 2, ak = (tid & 3) * 8;
    int bk = tid >> 3, bn8 = (tid & 7) * 8;
    int tm = tid >> 4, tn = tid & 15;
    float acc[4][4] = {};
    const float* Ap = A + (size_t)(bm + am) * K + ak;
    const float* Bp = B + (size_t)bk * N + bn + bn8;
    for (int k0 = 0; k0 < K; k0 += 32) {
        float4 a0 = *(const float4*)(Ap + k0);
        float4 a1 = *(const float4*)(Ap + k0 + 4);
        float4 b0 = *(const float4*)(Bp + (size_t)k0 * N);
        float4 b1 = *(const float4*)(Bp + (size_t)k0 * N + 4);
        __syncthreads();
        As[ak + 0][am] = a0.x; As[ak + 1][am] = a0.y;
        As[ak + 2][am] = a0.z; As[ak + 3][am] = a0.w;
        As[ak + 4][am] = a1.x; As[ak + 5][am] = a1.y;
        As[ak + 6][am] = a1.z; As[ak + 7][am] = a1.w;
        *(float4*)&Bs[bk][bn8]     = b0;
        *(float4*)&Bs[bk][bn8 + 4] = b1;
        __syncthreads();
#pragma unroll
        for (int kk = 0; kk < 32; kk++) {
            float4 a4 = *(const float4*)&As[kk][tm * 4];
            float4 b4 = *(const float4*)&Bs[kk][tn * 4];
            acc[0][0] += a4.x * b4.x; acc[0][1] += a4.x * b4.y; acc[0][2] += a4.x * b4.z; acc[0][3] += a4.x * b4.w;
            acc[1][0] += a4.y * b4.x; acc[1][1] += a4.y * b4.y; acc[1][2] += a4.y * b4.z; acc[1][3] += a4.y * b4.w;
            acc[2][0] += a4.z * b4.x; acc[2][1] += a4.z * b4.y; acc[2][2] += a4.z * b4.z; acc[2][3] += a4.z * b4.w;
            acc[3][0] += a4.w * b4.x; acc[3][1] += a4.w * b4.y; acc[3][2] += a4.w * b4.z; acc[3][3] += a4.w * b4.w;
        }
    }
    float bvr[4];
#pragma unroll
    for (int s = 0; s < 4; s++) bvr[s] = bias ? bias[bn + tn * 4 + s] : 0.0f;
#pragma unroll
    for (int r = 0; r < 4; r++) {
        float* cr = C + (size_t)(bm + tm * 4 + r) * N + bn + tn * 4;
        float4 o = { acc[r][0] + bvr[0], acc[r][1] + bvr[1], acc[r][2] + bvr[2], acc[r][3] + bvr[3] };
        *(float4*)cr = o;
    }
}

// ---------------------------------------------------------------- precompute u.k_j and vb.p_r
__global__ __launch_bounds__(256) void ukvb_kernel(const float* __restrict__ k,
                                                   const float* __restrict__ pp,
                                                   const float* __restrict__ u,
                                                   const float* __restrict__ vb,
                                                   float* __restrict__ ukg,
                                                   float* __restrict__ vbg) {
    int jid = blockIdx.x * 256 + threadIdx.x;
    if (jid < 2 * Hh * Sx) {
        int j = jid & 2047, h = (jid >> 11) & 15;
        int b = jid >> 15;
        const float* kr = k + ((size_t)(b * Sx + j)) * Dm + h * 64;
        const float* ur = u + h * 64;
        float s = 0.0f;
#pragma unroll
        for (int d4 = 0; d4 < 16; d4++)
            s += dot4(*(const float4*)(kr + d4 * 4), *(const float4*)(ur + d4 * 4));
        ukg[jid] = s;
    } else {
        int jid2 = jid - 2 * Hh * Sx;
        int r = jid2 & 2047, h = jid2 >> 11;
        const float* pr = pp + (size_t)r * Dm + h * 64;
        const float* vr = vb + h * 64;
        float s = 0.0f;
#pragma unroll
        for (int d4 = 0; d4 < 16; d4++)
            s += dot4(*(const float4*)(pr + d4 * 4), *(const float4*)(vr + d4 * 4));
        vbg[jid2] = s;
    }
}

// ---------------------------------------------------------------- MFMA helpers for flash
// 16x16x32 bf16 layouts (verified m89/m91/m120):
//   A[m][k]: m=lane&15, k=(lane>>4)*8+j      B[k][n]: n=lane&15, k=(lane>>4)*8+j
//   C/D   : col=lane&15, row=(lane>>4)*4+reg
__device__ __forceinline__ void wfill2(const unsigned short* Qs, const unsigned short* PW,
                                       int qrow0, int g, int l15, f32x4& d0, f32x4& d1) {
    f32x4 z = {0.f, 0.f, 0.f, 0.f};
    s16x8 a0 = *(const s16x8*)&Qs[(qrow0 + l15) * 72 + g * 8];
    s16x8 a1 = *(const s16x8*)&Qs[(qrow0 + l15) * 72 + 32 + g * 8];
    s16x8 b00 = *(const s16x8*)&PW[l15 * 72 + g * 8];
    s16x8 b01 = *(const s16x8*)&PW[l15 * 72 + 32 + g * 8];
    s16x8 b10 = *(const s16x8*)&PW[(16 + l15) * 72 + g * 8];
    s16x8 b11 = *(const s16x8*)&PW[(16 + l15) * 72 + 32 + g * 8];
    d0 = __builtin_amdgcn_mfma_f32_16x16x32_bf16(a0, b00, z, 0, 0, 0);
    d0 = __builtin_amdgcn_mfma_f32_16x16x32_bf16(a1, b01, d0, 0, 0, 0);
    d1 = __builtin_amdgcn_mfma_f32_16x16x32_bf16(a0, b10, z, 0, 0, 0);
    d1 = __builtin_amdgcn_mfma_f32_16x16x32_bf16(a1, b11, d1, 0, 0, 0);
}

// fill window chunk [vrb, vrb+32): W[row][slot] = (q_{i0+row+off} . p_v) + vb.p_v, 0 at v==Sx
__device__ __forceinline__ void window_fill(const unsigned short* Qs, const unsigned short* PW,
                                            float* Ws, const float* __restrict__ vbb,
                                            int a0, int vrb, int w, int g, int l15) {
    int vstart = a0 + vrb;
    f32x4 e0, e1;
    if (vstart + 31 <= Sx) {
        wfill2(Qs, PW, 16 * w, g, l15, e0, e1);
    } else if (vstart > Sx) {
        wfill2(Qs, PW, 16 * w + 1, g, l15, e0, e1);
    } else {
        f32x4 d0, d1, f0, f1;
        wfill2(Qs, PW, 16 * w,     g, l15, d0, d1);
        wfill2(Qs, PW, 16 * w + 1, g, l15, f0, f1);
        int v0 = vstart + l15, v1 = vstart + 16 + l15;
#pragma unroll
        for (int r = 0; r < 4; r++) {
            e0[r] = (v0 > Sx) ? f0[r] : d0[r];
            e1[r] = (v1 > Sx) ? f1[r] : d1[r];
        }
    }
    int v0 = vstart + l15, v1 = vstart + 16 + l15;
    int pc0 = v0 < Sx ? v0 : v0 - Sx - 1;
    int pc1 = v1 < Sx ? v1 : v1 - Sx - 1;
    float vb0 = (v0 == Sx) ? 0.0f : vbb[pc0];
    float vb1 = (v1 == Sx) ? 0.0f : vbb[pc1];
    int sl0 = (vrb + l15) % 96;
    int sl1 = (vrb + 16 + l15) % 96;
    int rbase = 16 * w + 4 * g;
#pragma unroll
    for (int r = 0; r < 4; r++) {
        Ws[(rbase + r) * 97 + sl0] = (v0 == Sx) ? 0.0f : e0[r] + vb0;
        Ws[(rbase + r) * 97 + sl1] = (v1 == Sx) ? 0.0f : e1[r] + vb1;
    }
}

// ---------------------------------------------------------------- flash attention, bf16 MFMA core
// block = (b, h, 64-query tile); wave w owns query rows 16w..16w+15.
// j-tiles of 32.  Rolling pos window Ws[64][96 circ] in fp32 (wave-local rows).
__global__ __launch_bounds__(256, 3) void flash_kernel(const float* __restrict__ q,
                                                       const float* __restrict__ k,
                                                       const float* __restrict__ v,
                                                       const float* __restrict__ pp,
                                                       const float* __restrict__ ukg,
                                                       const float* __restrict__ vbg,
                                                       float* __restrict__ head) {
    __shared__ unsigned short Qs[65 * 72];   // bf16 Q rows (row 64 = next i-tile's first row)
    __shared__ unsigned short Kt[32 * 72];   // bf16 K-tile  [j][d]
    __shared__ unsigned short PW[32 * 72];   // bf16 staged p-columns [vcol][d]
    __shared__ unsigned short VT[64 * 40];   // bf16 V-tile transposed [d][j]
    __shared__ unsigned short PA[64 * 40];   // bf16 probs [query][j] (wave-local strips)
    __shared__ float Ws[64 * 97];            // fp32 rolling window

    int tid = threadIdx.x;
    int blk = blockIdx.x;
    int it = blk & 31, h = (blk >> 5) & 15, b = blk >> 9;
    int i0 = it * 64;
    int a0 = 1984 - i0;

    const float* qb  = q   + ((size_t)b * Sx) * Dm + h * 64;
    const float* kb  = k   + ((size_t)b * Sx) * Dm + h * 64;
    const float* vb2 = v   + ((size_t)b * Sx) * Dm + h * 64;
    const float* ppb = pp  + h * 64;
    const float* ukb = ukg + (size_t)(b * Hh + h) * Sx;
    const float* vbb = vbg + (size_t)h * Sx;

    int w   = tid >> 6;
    int ln  = tid & 63;
    int g   = ln >> 4;
    int l15 = ln & 15;
    int rv  = tid >> 3, ch = tid & 7;      // staging: row, 8-dim chunk

    // ---- stage Q (65 rows, bf16)
    for (int c = tid; c < 65 * 8; c += 256) {
        int row = c >> 3, cc = c & 7;
        int i = i0 + row;
        s16x8 tv = {0, 0, 0, 0, 0, 0, 0, 0};
        if (i < Sx) tv = cvt8(qb + (size_t)i * Dm + cc * 8);
        *(s16x8*)&Qs[row * 72 + cc * 8] = tv;
    }

    // ---- prologue: window chunks vrb = 0, 32, 64
    for (int f = 0; f < 3; f++) {
        int vrb = f * 32;
        __syncthreads();
        {
            int vv = a0 + vrb + rv;
            s16x8 tv = {0, 0, 0, 0, 0, 0, 0, 0};
            if (vv != Sx) {
                int pc = vv < Sx ? vv : vv - Sx - 1;
                tv = cvt8(ppb + (size_t)pc * Dm + ch * 8);
            }
            *(s16x8*)&PW[rv * 72 + ch * 8] = tv;
        }
        __syncthreads();
        window_fill(Qs, PW, Ws, vbb, a0, vrb, w, g, l15);
    }

    f32x4 O[4] = {{0.f,0.f,0.f,0.f},{0.f,0.f,0.f,0.f},{0.f,0.f,0.f,0.f},{0.f,0.f,0.f,0.f}};
    float m_i[4] = {-1e30f, -1e30f, -1e30f, -1e30f};
    float l_i[4] = {0.f, 0.f, 0.f, 0.f};
    int rbase = 16 * w + 4 * g;

    for (int t = 0; t < 64; t++) {
        int j0 = t * 32;
        __syncthreads();   // B0: prior tile's Kt/PW/VT consumers done
        {   // stage K-tile (bf16), V-tile transposed, PW chunk (t>=1)
            s16x8 kv = cvt8(kb + (size_t)(j0 + rv) * Dm + ch * 8);
            *(s16x8*)&Kt[rv * 72 + ch * 8] = kv;
            const float* vsrc = vb2 + (size_t)(j0 + rv) * Dm + ch * 8;
            float4 v0 = *(const float4*)vsrc;
            float4 v1 = *(const float4*)(vsrc + 4);
            VT[(ch * 8 + 0) * 40 + rv] = f2bf(v0.x);
            VT[(ch * 8 + 1) * 40 + rv] = f2bf(v0.y);
            VT[(ch * 8 + 2) * 40 + rv] = f2bf(v0.z);
            VT[(ch * 8 + 3) * 40 + rv] = f2bf(v0.w);
            VT[(ch * 8 + 4) * 40 + rv] = f2bf(v1.x);
            VT[(ch * 8 + 5) * 40 + rv] = f2bf(v1.y);
            VT[(ch * 8 + 6) * 40 + rv] = f2bf(v1.z);
            VT[(ch * 8 + 7) * 40 + rv] = f2bf(v1.w);
            if (t >= 1) {
                int vv = a0 + (t + 2) * 32 + rv;
                s16x8 tv = {0, 0, 0, 0, 0, 0, 0, 0};
                if (vv != Sx) {
                    int pc = vv < Sx ? vv : vv - Sx - 1;
                    tv = cvt8(ppb + (size_t)pc * Dm + ch * 8);
                }
                *(s16x8*)&PW[rv * 72 + ch * 8] = tv;
            }
        }
        float uk0 = ukb[j0 + l15];
        float uk1 = ukb[j0 + 16 + l15];
        __syncthreads();   // B1: tiles staged

        // ---- content scores via MFMA: S[16 rows][32 cols] per wave
        f32x4 s0, s1;
        {
            f32x4 z = {0.f, 0.f, 0.f, 0.f};
            s16x8 aq0 = *(const s16x8*)&Qs[(16 * w + l15) * 72 + g * 8];
            s16x8 aq1 = *(const s16x8*)&Qs[(16 * w + l15) * 72 + 32 + g * 8];
            s16x8 bk00 = *(const s16x8*)&Kt[l15 * 72 + g * 8];
            s16x8 bk01 = *(const s16x8*)&Kt[l15 * 72 + 32 + g * 8];
            s16x8 bk10 = *(const s16x8*)&Kt[(16 + l15) * 72 + g * 8];
            s16x8 bk11 = *(const s16x8*)&Kt[(16 + l15) * 72 + 32 + g * 8];
            s0 = __builtin_amdgcn_mfma_f32_16x16x32_bf16(aq0, bk00, z, 0, 0, 0);
            s0 = __builtin_amdgcn_mfma_f32_16x16x32_bf16(aq1, bk01, s0, 0, 0, 0);
            s1 = __builtin_amdgcn_mfma_f32_16x16x32_bf16(aq0, bk10, z, 0, 0, 0);
            s1 = __builtin_amdgcn_mfma_f32_16x16x32_bf16(aq1, bk11, s1, 0, 0, 0);
        }

        // ---- window fill vrb = j0+64 (wave-local; fresh slots read below)
        if (t >= 1) window_fill(Qs, PW, Ws, vbb, a0, j0 + 64, w, g, l15);

        // ---- combine + online softmax (C layout: row=rbase+r, cols l15 / l15+16)
        float p0v[4], p1v[4], alpha[4];
#pragma unroll
        for (int r = 0; r < 4; r++) {
            int row = rbase + r;
            float pos0 = Ws[row * 97 + (63 + j0 + l15 - row) % 96];
            float pos1 = Ws[row * 97 + (63 + j0 + 16 + l15 - row) % 96];
            float lg0 = (s0[r] + uk0 + pos0) * 0.125f;
            float lg1 = (s1[r] + uk1 + pos1) * 0.125f;
            float mx = fmaxf(lg0, lg1);
#pragma unroll
            for (int o = 1; o < 16; o <<= 1) mx = fmaxf(mx, __shfl_xor(mx, o, 64));
            float mn = fmaxf(m_i[r], mx);
            alpha[r] = __expf(m_i[r] - mn);
            float e0 = __expf(lg0 - mn), e1 = __expf(lg1 - mn);
            float ls = e0 + e1;
#pragma unroll
            for (int o = 1; o < 16; o <<= 1) ls += __shfl_xor(ls, o, 64);
            l_i[r] = l_i[r] * alpha[r] + ls;
            m_i[r] = mn;
            p0v[r] = e0; p1v[r] = e1;
        }
        // probs -> PA (bf16, wave-local strip), O rescale
#pragma unroll
        for (int r = 0; r < 4; r++) {
            PA[(rbase + r) * 40 + l15]      = f2bf(p0v[r]);
            PA[(rbase + r) * 40 + 16 + l15] = f2bf(p1v[r]);
        }
#pragma unroll
        for (int nt = 0; nt < 4; nt++)
#pragma unroll
            for (int r = 0; r < 4; r++) O[nt][r] *= alpha[r];

        // ---- O += P.V via MFMA (A = PA strip, in-wave DS ordering)
        {
            s16x8 ap = *(const s16x8*)&PA[(16 * w + l15) * 40 + g * 8];
#pragma unroll
            for (int nt = 0; nt < 4; nt++) {
                s16x8 bv = *(const s16x8*)&VT[(nt * 16 + l15) * 40 + g * 8];
                O[nt] = __builtin_amdgcn_mfma_f32_16x16x32_bf16(ap, bv, O[nt], 0, 0, 0);
            }
        }
    }

    // ---- epilogue
#pragma unroll
    for (int r = 0; r < 4; r++) {
        float inv = 1.0f / l_i[r];
        int grow = i0 + rbase + r;
        float* dst = head + ((size_t)(b * Sx + grow)) * Dm + h * 64 + l15;
        dst[0]  = O[0][r] * inv;
        dst[16] = O[1][r] * inv;
        dst[32] = O[2][r] * inv;
        dst[48] = O[3][r] * inv;
    }
}

// ---------------------------------------------------------------- launcher
extern "C" void kernel_launch(void* const* d_in, const int* in_sizes, int n_in,
                              void* d_out, int out_size, void* d_ws, size_t ws_size,
                              hipStream_t stream) {
    const float* x    = (const float*)d_in[0];
    const float* ln_g = (const float*)d_in[1];
    const float* ln_b = (const float*)d_in[2];
    const float* Wq   = (const float*)d_in[3];
    const float* bq   = (const float*)d_in[4];
    const float* Wk   = (const float*)d_in[5];
    const float* bk   = (const float*)d_in[6];
    const float* Wv   = (const float*)d_in[7];
    const float* bv   = (const float*)d_in[8];
    const float* Wp   = (const float*)d_in[9];
    const float* Wo   = (const float*)d_in[10];
    const float* bo   = (const float*)d_in[11];
    const float* ub   = (const float*)d_in[12];
    const float* vbias= (const float*)d_in[13];

    float* out = (float*)d_out;
    float* ws  = (float*)d_ws;

    const int MROWS = 2 * Sx;                     // 4096
    float* xn   = out;                            // alias; final GEMM rewrites out
    float* qbuf = ws;
    float* kbuf = ws + 4u  * 1024 * 1024;
    float* vbuf = ws + 8u  * 1024 * 1024;
    float* pe   = ws + 12u * 1024 * 1024;         // reused as ukg/vbg after pp GEMM
    float* pp   = ws + 14u * 1024 * 1024;
    float* head = ws + 16u * 1024 * 1024;
    float* ukg  = pe;
    float* vbg  = pe + 2 * Hh * Sx;

    ln_kernel<<<MROWS, 256, 0, stream>>>(x, ln_g, ln_b, xn);
    pe_kernel<<<Sx * 512 / 256, 256, 0, stream>>>(pe);

    dim3 g1(Dm / 64, MROWS / 64);
    sgemm64<<<g1, 256, 0, stream>>>(xn, Wq, bq, qbuf, MROWS, Dm, Dm);
    sgemm64<<<g1, 256, 0, stream>>>(xn, Wk, bk, kbuf, MROWS, Dm, Dm);
    sgemm64<<<g1, 256, 0, stream>>>(xn, Wv, bv, vbuf, MROWS, Dm, Dm);
    dim3 g2(Dm / 64, Sx / 64);
    sgemm64<<<g2, 256, 0, stream>>>(pe, Wp, nullptr, pp, Sx, Dm, Dm);

    ukvb_kernel<<<(2 * Hh * Sx + Hh * Sx) / 256, 256, 0, stream>>>(kbuf, pp, ub, vbias, ukg, vbg);

    flash_kernel<<<2 * Hh * 32, 256, 0, stream>>>(qbuf, kbuf, vbuf, pp, ukg, vbg, head);

    sgemm64<<<g1, 256, 0, stream>>>(head, Wo, bo, out, MROWS, Dm, Dm);
}

// Round 5
// 713.215 us; speedup vs baseline: 24.8531x; 1.4911x over previous
//
#include <hip/hip_runtime.h>
#include <hip/hip_bf16.h>
#include <math.h>

#define Dm   1024
#define Hh   16
#define Sx   2048

typedef short s16x8 __attribute__((ext_vector_type(8)));
typedef float f32x4 __attribute__((ext_vector_type(4)));
typedef unsigned short u16;

__device__ __forceinline__ float dot4(float4 a, float4 b) {
    return a.x * b.x + a.y * b.y + a.z * b.z + a.w * b.w;
}
__device__ __forceinline__ float wave_sum64(float v) {
#pragma unroll
    for (int o = 32; o > 0; o >>= 1) v += __shfl_xor(v, o, 64);
    return v;
}
__device__ __forceinline__ u16 f2bf(float x) {
    unsigned int u = __float_as_uint(x);
    unsigned int r = u + 0x7FFFu + ((u >> 16) & 1u);
    return (u16)(r >> 16);
}
__device__ __forceinline__ float bf2f(u16 h) {
    return __uint_as_float(((unsigned int)h) << 16);
}
__device__ __forceinline__ s16x8 cvt8(const float* src) {
    float4 f0 = *(const float4*)src;
    float4 f1 = *(const float4*)(src + 4);
    s16x8 t;
    t[0] = (short)f2bf(f0.x); t[1] = (short)f2bf(f0.y);
    t[2] = (short)f2bf(f0.z); t[3] = (short)f2bf(f0.w);
    t[4] = (short)f2bf(f1.x); t[5] = (short)f2bf(f1.y);
    t[6] = (short)f2bf(f1.z); t[7] = (short)f2bf(f1.w);
    return t;
}

// ---------------------------------------------------------------- LayerNorm
__global__ __launch_bounds__(256) void ln_kernel(const float* __restrict__ x,
                                                 const float* __restrict__ g,
                                                 const float* __restrict__ b,
                                                 float* __restrict__ out) {
    int row = blockIdx.x;
    int tid = threadIdx.x;
    const float4* xr = (const float4*)(x + (size_t)row * Dm);
    float4 v = xr[tid];
    float s  = v.x + v.y + v.z + v.w;
    float ss = v.x * v.x + v.y * v.y + v.z * v.z + v.w * v.w;
    __shared__ float rbuf[8];
    s  = wave_sum64(s);
    ss = wave_sum64(ss);
    if ((tid & 63) == 0) { rbuf[tid >> 6] = s; rbuf[4 + (tid >> 6)] = ss; }
    __syncthreads();
    float mean = (rbuf[0] + rbuf[1] + rbuf[2] + rbuf[3]) * (1.0f / Dm);
    float msq  = (rbuf[4] + rbuf[5] + rbuf[6] + rbuf[7]) * (1.0f / Dm);
    float var  = msq - mean * mean;
    float rstd = 1.0f / sqrtf(var + 1e-5f);
    float4 gg = ((const float4*)g)[tid];
    float4 bb = ((const float4*)b)[tid];
    float4 o;
    o.x = (v.x - mean) * rstd * gg.x + bb.x;
    o.y = (v.y - mean) * rstd * gg.y + bb.y;
    o.z = (v.z - mean) * rstd * gg.z + bb.z;
    o.w = (v.w - mean) * rstd * gg.w + bb.w;
    ((float4*)(out + (size_t)row * Dm))[tid] = o;
}

// ---------------------------------------------------------------- sinusoidal PE
__global__ __launch_bounds__(256) void pe_kernel(float* __restrict__ pe) {
    int idx = blockIdx.x * 256 + threadIdx.x;
    int r = idx >> 9;
    int t = idx & 511;
    double div = exp((double)(2 * t) * (-9.210340371976184 / 1024.0));
    double ang = (double)r * div;
    pe[(size_t)r * Dm + 2 * t]     = (float)sin(ang);
    pe[(size_t)r * Dm + 2 * t + 1] = (float)cos(ang);
}

// ---------------------------------------------------------------- weight transpose + bf16 hi/lo split
// W [K=1024][N=1024] fp32 -> WT halfwords: WT[n*2048 + k] = hi(W[k][n]),
//                                          WT[n*2048 + 1024 + k] = lo(W[k][n])
__global__ __launch_bounds__(256) void wconv_kernel(const float* __restrict__ W0,
                                                    const float* __restrict__ W1,
                                                    const float* __restrict__ W2,
                                                    const float* __restrict__ W3,
                                                    const float* __restrict__ W4,
                                                    u16* __restrict__ WT) {
    int wz = blockIdx.z;
    const float* W = (wz == 0) ? W0 : (wz == 1) ? W1 : (wz == 2) ? W2 : (wz == 3) ? W3 : W4;
    u16* T = WT + (size_t)wz * 1024 * 2048;
    __shared__ float tile[32][33];
    int n0 = blockIdx.x * 32, k0 = blockIdx.y * 32;
    int tx = threadIdx.x & 31, ty = threadIdx.x >> 5;   // ty 0..7
#pragma unroll
    for (int r = 0; r < 32; r += 8)
        tile[ty + r][tx] = W[(size_t)(k0 + ty + r) * 1024 + n0 + tx];
    __syncthreads();
#pragma unroll
    for (int r = 0; r < 32; r += 8) {
        int n = ty + r;
        float x = tile[tx][n];            // W[k0+tx][n0+n]
        u16 h = f2bf(x);
        float rem = x - bf2f(h);
        u16 l = f2bf(rem);
        T[(size_t)(n0 + n) * 2048 + k0 + tx]        = h;
        T[(size_t)(n0 + n) * 2048 + 1024 + k0 + tx] = l;
    }
}

// ---------------------------------------------------------------- bf16x3 MFMA GEMM
// C[M,1024] = A[M,1024] @ W + bias, W pre-split in WT ([n][k] hi|lo).
// Tile 64(M) x 128(N), BK=32, 256 threads; wave w: rows 32*(w&1), cols 64*(w>>1).
// Error vs fp32: missing lo*lo + split residual ~2^-17|a||b| per term -> ~1e-5 abs.
__global__ __launch_bounds__(256, 4) void gemm_bf16x3(const float* __restrict__ A,
                                                      const u16* __restrict__ WT,
                                                      const float* __restrict__ bias,
                                                      float* __restrict__ C, int M) {
    const int K = 1024, N = 1024;
    __shared__ __align__(16) u16 Ah[64 * 72];    // [m][ hi(32) | lo(32) | pad ]
    __shared__ __align__(16) u16 Bh[128 * 72];   // [n][ hi(32) | lo(32) | pad ]
    int tid = threadIdx.x;
    int bn = blockIdx.x * 128, bm = blockIdx.y * 64;
    int ar = tid >> 2, ac = (tid & 3) * 8;       // A staging: row, col-chunk
    int br = tid >> 1, bs = (tid & 1);           // B staging: row, hi/lo seg
    int w = tid >> 6, ln = tid & 63, g = ln >> 4, l15 = ln & 15;
    int wm = (w & 1) * 32, wn = (w >> 1) * 64;

    const float* Ap = A + (size_t)(bm + ar) * K + ac;
    const u16*   Bp = WT + (size_t)(bn + br) * 2048 + bs * 1024;
    u16* Aw = &Ah[ar * 72 + ac];
    u16* Bw = &Bh[br * 72 + bs * 32];

    f32x4 acc[2][4] = {};

    for (int k0 = 0; k0 < K; k0 += 32) {
        // prefetch (regs) while LDS still owned by previous compute
        float4 a0 = *(const float4*)(Ap + k0);
        float4 a1 = *(const float4*)(Ap + k0 + 4);
        s16x8 wv0 = *(const s16x8*)(Bp + k0);
        s16x8 wv1 = *(const s16x8*)(Bp + k0 + 8);
        s16x8 wv2 = *(const s16x8*)(Bp + k0 + 16);
        s16x8 wv3 = *(const s16x8*)(Bp + k0 + 24);
        __syncthreads();
        {
            float av[8] = {a0.x, a0.y, a0.z, a0.w, a1.x, a1.y, a1.z, a1.w};
            s16x8 hv, lv;
#pragma unroll
            for (int i = 0; i < 8; i++) {
                u16 h = f2bf(av[i]);
                hv[i] = (short)h;
                lv[i] = (short)f2bf(av[i] - bf2f(h));
            }
            *(s16x8*)Aw        = hv;
            *(s16x8*)(Aw + 32) = lv;
            *(s16x8*)Bw        = wv0;
            *(s16x8*)(Bw + 8)  = wv1;
            *(s16x8*)(Bw + 16) = wv2;
            *(s16x8*)(Bw + 24) = wv3;
        }
        __syncthreads();
        s16x8 ah0 = *(const s16x8*)&Ah[(wm + l15) * 72 + g * 8];
        s16x8 al0 = *(const s16x8*)&Ah[(wm + l15) * 72 + 32 + g * 8];
        s16x8 ah1 = *(const s16x8*)&Ah[(wm + 16 + l15) * 72 + g * 8];
        s16x8 al1 = *(const s16x8*)&Ah[(wm + 16 + l15) * 72 + 32 + g * 8];
#pragma unroll
        for (int nt = 0; nt < 4; nt++) {
            int n = (wn + 16 * nt + l15) * 72;
            s16x8 bh = *(const s16x8*)&Bh[n + g * 8];
            s16x8 bl = *(const s16x8*)&Bh[n + 32 + g * 8];
            acc[0][nt] = __builtin_amdgcn_mfma_f32_16x16x32_bf16(ah0, bh, acc[0][nt], 0, 0, 0);
            acc[0][nt] = __builtin_amdgcn_mfma_f32_16x16x32_bf16(al0, bh, acc[0][nt], 0, 0, 0);
            acc[0][nt] = __builtin_amdgcn_mfma_f32_16x16x32_bf16(ah0, bl, acc[0][nt], 0, 0, 0);
            acc[1][nt] = __builtin_amdgcn_mfma_f32_16x16x32_bf16(ah1, bh, acc[1][nt], 0, 0, 0);
            acc[1][nt] = __builtin_amdgcn_mfma_f32_16x16x32_bf16(al1, bh, acc[1][nt], 0, 0, 0);
            acc[1][nt] = __builtin_amdgcn_mfma_f32_16x16x32_bf16(ah1, bl, acc[1][nt], 0, 0, 0);
        }
    }

    float bv[4];
#pragma unroll
    for (int nt = 0; nt < 4; nt++)
        bv[nt] = bias ? bias[bn + wn + 16 * nt + l15] : 0.0f;
#pragma unroll
    for (int mt = 0; mt < 2; mt++)
#pragma unroll
        for (int r = 0; r < 4; r++) {
            int row = bm + wm + 16 * mt + g * 4 + r;
            float* cp = C + (size_t)row * N + bn + wn + l15;
#pragma unroll
            for (int nt = 0; nt < 4; nt++)
                cp[16 * nt] = acc[mt][nt][r] + bv[nt];
        }
}

// ---------------------------------------------------------------- SGEMM 64x64 (fallback if ws too small)
__global__ __launch_bounds__(256) void sgemm64(const float* __restrict__ A,
                                               const float* __restrict__ B,
                                               const float* __restrict__ bias,
                                               float* __restrict__ C,
                                               int M, int N, int K) {
    __shared__ float As[32][68];
    __shared__ float Bs[32][68];
    int tid = threadIdx.x;
    int bn = blockIdx.x * 64, bm = blockIdx.y * 64;
    int am = tid >> 2, ak = (tid & 3) * 8;
    int bk = tid >> 3, bn8 = (tid & 7) * 8;
    int tm = tid >> 4, tn = tid & 15;
    float acc[4][4] = {};
    const float* Ap = A + (size_t)(bm + am) * K + ak;
    const float* Bp = B + (size_t)bk * N + bn + bn8;
    for (int k0 = 0; k0 < K; k0 += 32) {
        float4 a0 = *(const float4*)(Ap + k0);
        float4 a1 = *(const float4*)(Ap + k0 + 4);
        float4 b0 = *(const float4*)(Bp + (size_t)k0 * N);
        float4 b1 = *(const float4*)(Bp + (size_t)k0 * N + 4);
        __syncthreads();
        As[ak + 0][am] = a0.x; As[ak + 1][am] = a0.y;
        As[ak + 2][am] = a0.z; As[ak + 3][am] = a0.w;
        As[ak + 4][am] = a1.x; As[ak + 5][am] = a1.y;
        As[ak + 6][am] = a1.z; As[ak + 7][am] = a1.w;
        *(float4*)&Bs[bk][bn8]     = b0;
        *(float4*)&Bs[bk][bn8 + 4] = b1;
        __syncthreads();
#pragma unroll
        for (int kk = 0; kk < 32; kk++) {
            float4 a4 = *(const float4*)&As[kk][tm * 4];
            float4 b4 = *(const float4*)&Bs[kk][tn * 4];
            acc[0][0] += a4.x * b4.x; acc[0][1] += a4.x * b4.y; acc[0][2] += a4.x * b4.z; acc[0][3] += a4.x * b4.w;
            acc[1][0] += a4.y * b4.x; acc[1][1] += a4.y * b4.y; acc[1][2] += a4.y * b4.z; acc[1][3] += a4.y * b4.w;
            acc[2][0] += a4.z * b4.x; acc[2][1] += a4.z * b4.y; acc[2][2] += a4.z * b4.z; acc[2][3] += a4.z * b4.w;
            acc[3][0] += a4.w * b4.x; acc[3][1] += a4.w * b4.y; acc[3][2] += a4.w * b4.z; acc[3][3] += a4.w * b4.w;
        }
    }
    float bvr[4];
#pragma unroll
    for (int s = 0; s < 4; s++) bvr[s] = bias ? bias[bn + tn * 4 + s] : 0.0f;
#pragma unroll
    for (int r = 0; r < 4; r++) {
        float* cr = C + (size_t)(bm + tm * 4 + r) * N + bn + tn * 4;
        float4 o = { acc[r][0] + bvr[0], acc[r][1] + bvr[1], acc[r][2] + bvr[2], acc[r][3] + bvr[3] };
        *(float4*)cr = o;
    }
}

// ---------------------------------------------------------------- precompute u.k_j and vb.p_r
__global__ __launch_bounds__(256) void ukvb_kernel(const float* __restrict__ k,
                                                   const float* __restrict__ pp,
                                                   const float* __restrict__ u,
                                                   const float* __restrict__ vb,
                                                   float* __restrict__ ukg,
                                                   float* __restrict__ vbg) {
    int jid = blockIdx.x * 256 + threadIdx.x;
    if (jid < 2 * Hh * Sx) {
        int j = jid & 2047, h = (jid >> 11) & 15;
        int b = jid >> 15;
        const float* kr = k + ((size_t)(b * Sx + j)) * Dm + h * 64;
        const float* ur = u + h * 64;
        float s = 0.0f;
#pragma unroll
        for (int d4 = 0; d4 < 16; d4++)
            s += dot4(*(const float4*)(kr + d4 * 4), *(const float4*)(ur + d4 * 4));
        ukg[jid] = s;
    } else {
        int jid2 = jid - 2 * Hh * Sx;
        int r = jid2 & 2047, h = jid2 >> 11;
        const float* pr = pp + (size_t)r * Dm + h * 64;
        const float* vr = vb + h * 64;
        float s = 0.0f;
#pragma unroll
        for (int d4 = 0; d4 < 16; d4++)
            s += dot4(*(const float4*)(pr + d4 * 4), *(const float4*)(vr + d4 * 4));
        vbg[jid2] = s;
    }
}

// ---------------------------------------------------------------- MFMA helpers for flash
__device__ __forceinline__ void wfill2(const u16* Qs, const u16* PW,
                                       int qrow0, int g, int l15, f32x4& d0, f32x4& d1) {
    f32x4 z = {0.f, 0.f, 0.f, 0.f};
    s16x8 a0 = *(const s16x8*)&Qs[(qrow0 + l15) * 72 + g * 8];
    s16x8 a1 = *(const s16x8*)&Qs[(qrow0 + l15) * 72 + 32 + g * 8];
    s16x8 b00 = *(const s16x8*)&PW[l15 * 72 + g * 8];
    s16x8 b01 = *(const s16x8*)&PW[l15 * 72 + 32 + g * 8];
    s16x8 b10 = *(const s16x8*)&PW[(16 + l15) * 72 + g * 8];
    s16x8 b11 = *(const s16x8*)&PW[(16 + l15) * 72 + 32 + g * 8];
    d0 = __builtin_amdgcn_mfma_f32_16x16x32_bf16(a0, b00, z, 0, 0, 0);
    d0 = __builtin_amdgcn_mfma_f32_16x16x32_bf16(a1, b01, d0, 0, 0, 0);
    d1 = __builtin_amdgcn_mfma_f32_16x16x32_bf16(a0, b10, z, 0, 0, 0);
    d1 = __builtin_amdgcn_mfma_f32_16x16x32_bf16(a1, b11, d1, 0, 0, 0);
}

__device__ __forceinline__ void window_fill(const u16* Qs, const u16* PW,
                                            float* Ws, const float* __restrict__ vbb,
                                            int a0, int vrb, int w, int g, int l15) {
    int vstart = a0 + vrb;
    f32x4 e0, e1;
    if (vstart + 31 <= Sx) {
        wfill2(Qs, PW, 16 * w, g, l15, e0, e1);
    } else if (vstart > Sx) {
        wfill2(Qs, PW, 16 * w + 1, g, l15, e0, e1);
    } else {
        f32x4 d0, d1, f0, f1;
        wfill2(Qs, PW, 16 * w,     g, l15, d0, d1);
        wfill2(Qs, PW, 16 * w + 1, g, l15, f0, f1);
        int v0 = vstart + l15, v1 = vstart + 16 + l15;
#pragma unroll
        for (int r = 0; r < 4; r++) {
            e0[r] = (v0 > Sx) ? f0[r] : d0[r];
            e1[r] = (v1 > Sx) ? f1[r] : d1[r];
        }
    }
    int v0 = vstart + l15, v1 = vstart + 16 + l15;
    int pc0 = v0 < Sx ? v0 : v0 - Sx - 1;
    int pc1 = v1 < Sx ? v1 : v1 - Sx - 1;
    float vb0 = (v0 == Sx) ? 0.0f : vbb[pc0];
    float vb1 = (v1 == Sx) ? 0.0f : vbb[pc1];
    int sl0 = (vrb + l15) % 96;
    int sl1 = (vrb + 16 + l15) % 96;
    int rbase = 16 * w + 4 * g;
#pragma unroll
    for (int r = 0; r < 4; r++) {
        Ws[(rbase + r) * 97 + sl0] = (v0 == Sx) ? 0.0f : e0[r] + vb0;
        Ws[(rbase + r) * 97 + sl1] = (v1 == Sx) ? 0.0f : e1[r] + vb1;
    }
}

// ---------------------------------------------------------------- flash attention, bf16 MFMA core
__global__ __launch_bounds__(256, 3) void flash_kernel(const float* __restrict__ q,
                                                       const float* __restrict__ k,
                                                       const float* __restrict__ v,
                                                       const float* __restrict__ pp,
                                                       const float* __restrict__ ukg,
                                                       const float* __restrict__ vbg,
                                                       float* __restrict__ head) {
    __shared__ u16 Qs[65 * 72];
    __shared__ u16 Kt[32 * 72];
    __shared__ u16 PW[32 * 72];
    __shared__ u16 VT[64 * 40];
    __shared__ u16 PA[64 * 40];
    __shared__ float Ws[64 * 97];

    int tid = threadIdx.x;
    int blk = blockIdx.x;
    int it = blk & 31, h = (blk >> 5) & 15, b = blk >> 9;
    int i0 = it * 64;
    int a0 = 1984 - i0;

    const float* qb  = q   + ((size_t)b * Sx) * Dm + h * 64;
    const float* kb  = k   + ((size_t)b * Sx) * Dm + h * 64;
    const float* vb2 = v   + ((size_t)b * Sx) * Dm + h * 64;
    const float* ppb = pp  + h * 64;
    const float* ukb = ukg + (size_t)(b * Hh + h) * Sx;
    const float* vbb = vbg + (size_t)h * Sx;

    int w   = tid >> 6;
    int ln  = tid & 63;
    int g   = ln >> 4;
    int l15 = ln & 15;
    int rv  = tid >> 3, ch = tid & 7;

    for (int c = tid; c < 65 * 8; c += 256) {
        int row = c >> 3, cc = c & 7;
        int i = i0 + row;
        s16x8 tv = {0, 0, 0, 0, 0, 0, 0, 0};
        if (i < Sx) tv = cvt8(qb + (size_t)i * Dm + cc * 8);
        *(s16x8*)&Qs[row * 72 + cc * 8] = tv;
    }

    for (int f = 0; f < 3; f++) {
        int vrb = f * 32;
        __syncthreads();
        {
            int vv = a0 + vrb + rv;
            s16x8 tv = {0, 0, 0, 0, 0, 0, 0, 0};
            if (vv != Sx) {
                int pc = vv < Sx ? vv : vv - Sx - 1;
                tv = cvt8(ppb + (size_t)pc * Dm + ch * 8);
            }
            *(s16x8*)&PW[rv * 72 + ch * 8] = tv;
        }
        __syncthreads();
        window_fill(Qs, PW, Ws, vbb, a0, vrb, w, g, l15);
    }

    f32x4 O[4] = {{0.f,0.f,0.f,0.f},{0.f,0.f,0.f,0.f},{0.f,0.f,0.f,0.f},{0.f,0.f,0.f,0.f}};
    float m_i[4] = {-1e30f, -1e30f, -1e30f, -1e30f};
    float l_i[4] = {0.f, 0.f, 0.f, 0.f};
    int rbase = 16 * w + 4 * g;

    for (int t = 0; t < 64; t++) {
        int j0 = t * 32;
        __syncthreads();
        {
            s16x8 kv = cvt8(kb + (size_t)(j0 + rv) * Dm + ch * 8);
            *(s16x8*)&Kt[rv * 72 + ch * 8] = kv;
            const float* vsrc = vb2 + (size_t)(j0 + rv) * Dm + ch * 8;
            float4 v0 = *(const float4*)vsrc;
            float4 v1 = *(const float4*)(vsrc + 4);
            VT[(ch * 8 + 0) * 40 + rv] = f2bf(v0.x);
            VT[(ch * 8 + 1) * 40 + rv] = f2bf(v0.y);
            VT[(ch * 8 + 2) * 40 + rv] = f2bf(v0.z);
            VT[(ch * 8 + 3) * 40 + rv] = f2bf(v0.w);
            VT[(ch * 8 + 4) * 40 + rv] = f2bf(v1.x);
            VT[(ch * 8 + 5) * 40 + rv] = f2bf(v1.y);
            VT[(ch * 8 + 6) * 40 + rv] = f2bf(v1.z);
            VT[(ch * 8 + 7) * 40 + rv] = f2bf(v1.w);
            if (t >= 1) {
                int vv = a0 + (t + 2) * 32 + rv;
                s16x8 tv = {0, 0, 0, 0, 0, 0, 0, 0};
                if (vv != Sx) {
                    int pc = vv < Sx ? vv : vv - Sx - 1;
                    tv = cvt8(ppb + (size_t)pc * Dm + ch * 8);
                }
                *(s16x8*)&PW[rv * 72 + ch * 8] = tv;
            }
        }
        float uk0 = ukb[j0 + l15];
        float uk1 = ukb[j0 + 16 + l15];
        __syncthreads();

        f32x4 s0, s1;
        {
            f32x4 z = {0.f, 0.f, 0.f, 0.f};
            s16x8 aq0 = *(const s16x8*)&Qs[(16 * w + l15) * 72 + g * 8];
            s16x8 aq1 = *(const s16x8*)&Qs[(16 * w + l15) * 72 + 32 + g * 8];
            s16x8 bk00 = *(const s16x8*)&Kt[l15 * 72 + g * 8];
            s16x8 bk01 = *(const s16x8*)&Kt[l15 * 72 + 32 + g * 8];
            s16x8 bk10 = *(const s16x8*)&Kt[(16 + l15) * 72 + g * 8];
            s16x8 bk11 = *(const s16x8*)&Kt[(16 + l15) * 72 + 32 + g * 8];
            s0 = __builtin_amdgcn_mfma_f32_16x16x32_bf16(aq0, bk00, z, 0, 0, 0);
            s0 = __builtin_amdgcn_mfma_f32_16x16x32_bf16(aq1, bk01, s0, 0, 0, 0);
            s1 = __builtin_amdgcn_mfma_f32_16x16x32_bf16(aq0, bk10, z, 0, 0, 0);
            s1 = __builtin_amdgcn_mfma_f32_16x16x32_bf16(aq1, bk11, s1, 0, 0, 0);
        }

        if (t >= 1) window_fill(Qs, PW, Ws, vbb, a0, j0 + 64, w, g, l15);

        float p0v[4], p1v[4], alpha[4];
#pragma unroll
        for (int r = 0; r < 4; r++) {
            int row = rbase + r;
            float pos0 = Ws[row * 97 + (63 + j0 + l15 - row) % 96];
            float pos1 = Ws[row * 97 + (63 + j0 + 16 + l15 - row) % 96];
            float lg0 = (s0[r] + uk0 + pos0) * 0.125f;
            float lg1 = (s1[r] + uk1 + pos1) * 0.125f;
            float mx = fmaxf(lg0, lg1);
#pragma unroll
            for (int o = 1; o < 16; o <<= 1) mx = fmaxf(mx, __shfl_xor(mx, o, 64));
            float mn = fmaxf(m_i[r], mx);
            alpha[r] = __expf(m_i[r] - mn);
            float e0 = __expf(lg0 - mn), e1 = __expf(lg1 - mn);
            float ls = e0 + e1;
#pragma unroll
            for (int o = 1; o < 16; o <<= 1) ls += __shfl_xor(ls, o, 64);
            l_i[r] = l_i[r] * alpha[r] + ls;
            m_i[r] = mn;
            p0v[r] = e0; p1v[r] = e1;
        }
#pragma unroll
        for (int r = 0; r < 4; r++) {
            PA[(rbase + r) * 40 + l15]      = f2bf(p0v[r]);
            PA[(rbase + r) * 40 + 16 + l15] = f2bf(p1v[r]);
        }
#pragma unroll
        for (int nt = 0; nt < 4; nt++)
#pragma unroll
            for (int r = 0; r < 4; r++) O[nt][r] *= alpha[r];

        {
            s16x8 ap = *(const s16x8*)&PA[(16 * w + l15) * 40 + g * 8];
#pragma unroll
            for (int nt = 0; nt < 4; nt++) {
                s16x8 bv = *(const s16x8*)&VT[(nt * 16 + l15) * 40 + g * 8];
                O[nt] = __builtin_amdgcn_mfma_f32_16x16x32_bf16(ap, bv, O[nt], 0, 0, 0);
            }
        }
    }

#pragma unroll
    for (int r = 0; r < 4; r++) {
        float inv = 1.0f / l_i[r];
        int grow = i0 + rbase + r;
        float* dst = head + ((size_t)(b * Sx + grow)) * Dm + h * 64 + l15;
        dst[0]  = O[0][r] * inv;
        dst[16] = O[1][r] * inv;
        dst[32] = O[2][r] * inv;
        dst[48] = O[3][r] * inv;
    }
}

// ---------------------------------------------------------------- launcher
extern "C" void kernel_launch(void* const* d_in, const int* in_sizes, int n_in,
                              void* d_out, int out_size, void* d_ws, size_t ws_size,
                              hipStream_t stream) {
    const float* x    = (const float*)d_in[0];
    const float* ln_g = (const float*)d_in[1];
    const float* ln_b = (const float*)d_in[2];
    const float* Wq   = (const float*)d_in[3];
    const float* bq   = (const float*)d_in[4];
    const float* Wk   = (const float*)d_in[5];
    const float* bk   = (const float*)d_in[6];
    const float* Wv   = (const float*)d_in[7];
    const float* bv   = (const float*)d_in[8];
    const float* Wp   = (const float*)d_in[9];
    const float* Wo   = (const float*)d_in[10];
    const float* bo   = (const float*)d_in[11];
    const float* ub   = (const float*)d_in[12];
    const float* vbias= (const float*)d_in[13];

    float* out = (float*)d_out;
    float* ws  = (float*)d_ws;

    const int MROWS = 2 * Sx;                     // 4096
    float* xn   = out;                            // alias; final GEMM rewrites out
    float* qbuf = ws;
    float* kbuf = ws + 4u  * 1024 * 1024;
    float* vbuf = ws + 8u  * 1024 * 1024;
    float* pe   = ws + 12u * 1024 * 1024;         // reused as ukg/vbg after pp GEMM
    float* pp   = ws + 14u * 1024 * 1024;
    float* head = ws + 16u * 1024 * 1024;
    float* ukg  = pe;
    float* vbg  = pe + 2 * Hh * Sx;
    u16*   WT   = (u16*)(ws + 20u * 1024 * 1024); // 5 x 4 MiB bf16 hi/lo weights

    const size_t WS_NEEDED = (size_t)20 * 1024 * 1024 * 4 + (size_t)5 * 1024 * 2048 * 2; // 100 MiB
    bool use_mfma = ws_size >= WS_NEEDED;

    ln_kernel<<<MROWS, 256, 0, stream>>>(x, ln_g, ln_b, xn);
    pe_kernel<<<Sx * 512 / 256, 256, 0, stream>>>(pe);

    if (use_mfma) {
        dim3 gw(32, 32, 5);
        wconv_kernel<<<gw, 256, 0, stream>>>(Wq, Wk, Wv, Wp, Wo, WT);
        dim3 g1(8, MROWS / 64);                   // (8, 64)
        dim3 g2(8, Sx / 64);                      // (8, 32)
        gemm_bf16x3<<<g1, 256, 0, stream>>>(xn, WT + 0u * 1024 * 2048, bq, qbuf, MROWS);
        gemm_bf16x3<<<g1, 256, 0, stream>>>(xn, WT + 1u * 1024 * 2048, bk, kbuf, MROWS);
        gemm_bf16x3<<<g1, 256, 0, stream>>>(xn, WT + 2u * 1024 * 2048, bv, vbuf, MROWS);
        gemm_bf16x3<<<g2, 256, 0, stream>>>(pe, WT + 3u * 1024 * 2048, nullptr, pp, Sx);

        ukvb_kernel<<<(2 * Hh * Sx + Hh * Sx) / 256, 256, 0, stream>>>(kbuf, pp, ub, vbias, ukg, vbg);
        flash_kernel<<<2 * Hh * 32, 256, 0, stream>>>(qbuf, kbuf, vbuf, pp, ukg, vbg, head);

        gemm_bf16x3<<<g1, 256, 0, stream>>>(head, WT + 4u * 1024 * 2048, bo, out, MROWS);
    } else {
        dim3 g1(Dm / 64, MROWS / 64);
        dim3 g2(Dm / 64, Sx / 64);
        sgemm64<<<g1, 256, 0, stream>>>(xn, Wq, bq, qbuf, MROWS, Dm, Dm);
        sgemm64<<<g1, 256, 0, stream>>>(xn, Wk, bk, kbuf, MROWS, Dm, Dm);
        sgemm64<<<g1, 256, 0, stream>>>(xn, Wv, bv, vbuf, MROWS, Dm, Dm);
        sgemm64<<<g2, 256, 0, stream>>>(pe, Wp, nullptr, pp, Sx, Dm, Dm);

        ukvb_kernel<<<(2 * Hh * Sx + Hh * Sx) / 256, 256, 0, stream>>>(kbuf, pp, ub, vbias, ukg, vbg);
        flash_kernel<<<2 * Hh * 32, 256, 0, stream>>>(qbuf, kbuf, vbuf, pp, ukg, vbg, head);

        sgemm64<<<g1, 256, 0, stream>>>(head, Wo, bo, out, MROWS, Dm, Dm);
    }
}

// Round 6
// 556.823 us; speedup vs baseline: 31.8335x; 1.2809x over previous
//
#include <hip/hip_runtime.h>
#include <hip/hip_bf16.h>
#include <math.h>

#define Dm   1024
#define Hh   16
#define Sx   2048

typedef short s16x8 __attribute__((ext_vector_type(8)));
typedef float f32x4 __attribute__((ext_vector_type(4)));
typedef unsigned short u16;
typedef u16 u16x4 __attribute__((ext_vector_type(4)));

__device__ __forceinline__ float wave_sum64(float v) {
#pragma unroll
    for (int o = 32; o > 0; o >>= 1) v += __shfl_xor(v, o, 64);
    return v;
}
__device__ __forceinline__ u16 f2bf(float x) {
    unsigned int u = __float_as_uint(x);
    unsigned int r = u + 0x7FFFu + ((u >> 16) & 1u);
    return (u16)(r >> 16);
}
__device__ __forceinline__ float bf2f(u16 h) {
    return __uint_as_float(((unsigned int)h) << 16);
}

// ---------------------------------------------------------------- LayerNorm -> pre-split bf16 hi|lo
__global__ __launch_bounds__(256) void ln_kernel(const float* __restrict__ x,
                                                 const float* __restrict__ g,
                                                 const float* __restrict__ b,
                                                 u16* __restrict__ out16) {
    int row = blockIdx.x;
    int tid = threadIdx.x;
    const float4* xr = (const float4*)(x + (size_t)row * Dm);
    float4 v = xr[tid];
    float s  = v.x + v.y + v.z + v.w;
    float ss = v.x * v.x + v.y * v.y + v.z * v.z + v.w * v.w;
    __shared__ float rbuf[8];
    s  = wave_sum64(s);
    ss = wave_sum64(ss);
    if ((tid & 63) == 0) { rbuf[tid >> 6] = s; rbuf[4 + (tid >> 6)] = ss; }
    __syncthreads();
    float mean = (rbuf[0] + rbuf[1] + rbuf[2] + rbuf[3]) * (1.0f / Dm);
    float msq  = (rbuf[4] + rbuf[5] + rbuf[6] + rbuf[7]) * (1.0f / Dm);
    float var  = msq - mean * mean;
    float rstd = 1.0f / sqrtf(var + 1e-5f);
    float4 gg = ((const float4*)g)[tid];
    float4 bb = ((const float4*)b)[tid];
    float o[4];
    o[0] = (v.x - mean) * rstd * gg.x + bb.x;
    o[1] = (v.y - mean) * rstd * gg.y + bb.y;
    o[2] = (v.z - mean) * rstd * gg.z + bb.z;
    o[3] = (v.w - mean) * rstd * gg.w + bb.w;
    u16x4 hi, lo;
#pragma unroll
    for (int i = 0; i < 4; i++) {
        u16 h = f2bf(o[i]);
        hi[i] = h;
        lo[i] = f2bf(o[i] - bf2f(h));
    }
    *(u16x4*)&out16[(size_t)row * 2048 + tid * 4]        = hi;
    *(u16x4*)&out16[(size_t)row * 2048 + 1024 + tid * 4] = lo;
}

// ---------------------------------------------------------------- sinusoidal PE -> pre-split bf16
__global__ __launch_bounds__(256) void pe_kernel(u16* __restrict__ pe16) {
    int idx = blockIdx.x * 256 + threadIdx.x;
    int r = idx >> 9;
    int t = idx & 511;
    double div = exp((double)(2 * t) * (-9.210340371976184 / 1024.0));
    double ang = (double)r * div;
    float sv = (float)sin(ang), cv = (float)cos(ang);
    u16 sh = f2bf(sv), chh = f2bf(cv);
    u16* row = pe16 + (size_t)r * 2048;
    row[2 * t]            = sh;
    row[2 * t + 1]        = chh;
    row[1024 + 2 * t]     = f2bf(sv - bf2f(sh));
    row[1024 + 2 * t + 1] = f2bf(cv - bf2f(chh));
}

// ---------------------------------------------------------------- weight transpose + bf16 hi/lo split
__global__ __launch_bounds__(256) void wconv_kernel(const float* __restrict__ W0,
                                                    const float* __restrict__ W1,
                                                    const float* __restrict__ W2,
                                                    const float* __restrict__ W3,
                                                    const float* __restrict__ W4,
                                                    u16* __restrict__ WT) {
    int wz = blockIdx.z;
    const float* W = (wz == 0) ? W0 : (wz == 1) ? W1 : (wz == 2) ? W2 : (wz == 3) ? W3 : W4;
    u16* T = WT + (size_t)wz * 1024 * 2048;
    __shared__ float tile[32][33];
    int n0 = blockIdx.x * 32, k0 = blockIdx.y * 32;
    int tx = threadIdx.x & 31, ty = threadIdx.x >> 5;
#pragma unroll
    for (int r = 0; r < 32; r += 8)
        tile[ty + r][tx] = W[(size_t)(k0 + ty + r) * 1024 + n0 + tx];
    __syncthreads();
#pragma unroll
    for (int r = 0; r < 32; r += 8) {
        int n = ty + r;
        float x = tile[tx][n];
        u16 h = f2bf(x);
        float rem = x - bf2f(h);
        T[(size_t)(n0 + n) * 2048 + k0 + tx]        = h;
        T[(size_t)(n0 + n) * 2048 + 1024 + k0 + tx] = f2bf(rem);
    }
}

// ---------------------------------------------------------------- bf16x3 MFMA GEMM (pre-split A and B)
// C = A @ W + bias; A16: [M][hi 1024 | lo 1024]; WT: [n][hi k | lo k].
// Out: fp32 C (if Cb==null) or bf16 Cb.
__global__ __launch_bounds__(256, 4) void gemm_bf16x3(const u16* __restrict__ A16,
                                                      const u16* __restrict__ WT,
                                                      const float* __restrict__ bias,
                                                      float* __restrict__ C,
                                                      u16* __restrict__ Cb, int M) {
    const int K = 1024, N = 1024;
    __shared__ __align__(16) u16 Ah[64 * 72];
    __shared__ __align__(16) u16 Bh[128 * 72];
    int tid = threadIdx.x;
    int bn = blockIdx.x * 128, bm = blockIdx.y * 64;
    int ar = tid >> 2, ac = (tid & 3) * 8;
    int br = tid >> 1, bs = (tid & 1);
    int w = tid >> 6, ln = tid & 63, g = ln >> 4, l15 = ln & 15;
    int wm = (w & 1) * 32, wn = (w >> 1) * 64;

    const u16* Ap = A16 + (size_t)(bm + ar) * 2048 + ac;
    const u16* Bp = WT + (size_t)(bn + br) * 2048 + bs * 1024;
    u16* Aw = &Ah[ar * 72 + ac];
    u16* Bw = &Bh[br * 72 + bs * 32];

    f32x4 acc[2][4] = {};
    s16x8 pah = *(const s16x8*)Ap;
    s16x8 pal = *(const s16x8*)(Ap + 1024);
    s16x8 pb0 = *(const s16x8*)Bp;
    s16x8 pb1 = *(const s16x8*)(Bp + 8);
    s16x8 pb2 = *(const s16x8*)(Bp + 16);
    s16x8 pb3 = *(const s16x8*)(Bp + 24);

    for (int k0 = 0; k0 < K; k0 += 32) {
        __syncthreads();
        *(s16x8*)Aw        = pah;
        *(s16x8*)(Aw + 32) = pal;
        *(s16x8*)Bw        = pb0;
        *(s16x8*)(Bw + 8)  = pb1;
        *(s16x8*)(Bw + 16) = pb2;
        *(s16x8*)(Bw + 24) = pb3;
        int kn = k0 + 32;
        if (kn < K) {
            pah = *(const s16x8*)(Ap + kn);
            pal = *(const s16x8*)(Ap + 1024 + kn);
            pb0 = *(const s16x8*)(Bp + kn);
            pb1 = *(const s16x8*)(Bp + kn + 8);
            pb2 = *(const s16x8*)(Bp + kn + 16);
            pb3 = *(const s16x8*)(Bp + kn + 24);
        }
        __syncthreads();
        s16x8 ah0 = *(const s16x8*)&Ah[(wm + l15) * 72 + g * 8];
        s16x8 al0 = *(const s16x8*)&Ah[(wm + l15) * 72 + 32 + g * 8];
        s16x8 ah1 = *(const s16x8*)&Ah[(wm + 16 + l15) * 72 + g * 8];
        s16x8 al1 = *(const s16x8*)&Ah[(wm + 16 + l15) * 72 + 32 + g * 8];
#pragma unroll
        for (int nt = 0; nt < 4; nt++) {
            int n = (wn + 16 * nt + l15) * 72;
            s16x8 bh = *(const s16x8*)&Bh[n + g * 8];
            s16x8 bl = *(const s16x8*)&Bh[n + 32 + g * 8];
            acc[0][nt] = __builtin_amdgcn_mfma_f32_16x16x32_bf16(ah0, bh, acc[0][nt], 0, 0, 0);
            acc[0][nt] = __builtin_amdgcn_mfma_f32_16x16x32_bf16(al0, bh, acc[0][nt], 0, 0, 0);
            acc[0][nt] = __builtin_amdgcn_mfma_f32_16x16x32_bf16(ah0, bl, acc[0][nt], 0, 0, 0);
            acc[1][nt] = __builtin_amdgcn_mfma_f32_16x16x32_bf16(ah1, bh, acc[1][nt], 0, 0, 0);
            acc[1][nt] = __builtin_amdgcn_mfma_f32_16x16x32_bf16(al1, bh, acc[1][nt], 0, 0, 0);
            acc[1][nt] = __builtin_amdgcn_mfma_f32_16x16x32_bf16(ah1, bl, acc[1][nt], 0, 0, 0);
        }
    }

    float bv[4];
#pragma unroll
    for (int nt = 0; nt < 4; nt++)
        bv[nt] = bias ? bias[bn + wn + 16 * nt + l15] : 0.0f;
#pragma unroll
    for (int mt = 0; mt < 2; mt++)
#pragma unroll
        for (int r = 0; r < 4; r++) {
            int row = bm + wm + 16 * mt + g * 4 + r;
            if (Cb) {
                u16* cp = Cb + (size_t)row * N + bn + wn + l15;
#pragma unroll
                for (int nt = 0; nt < 4; nt++)
                    cp[16 * nt] = f2bf(acc[mt][nt][r] + bv[nt]);
            } else {
                float* cp = C + (size_t)row * N + bn + wn + l15;
#pragma unroll
                for (int nt = 0; nt < 4; nt++)
                    cp[16 * nt] = acc[mt][nt][r] + bv[nt];
            }
        }
}

// ---------------------------------------------------------------- V transpose to tiled [b][h][jt][d][32]
__global__ __launch_bounds__(256) void vtrans_kernel(const u16* __restrict__ v,
                                                     u16* __restrict__ vT) {
    __shared__ u16 L[32 * 72];
    int jt = blockIdx.x, h = blockIdx.y, b = blockIdx.z;
    int tid = threadIdx.x;
    int row = tid >> 3, cc = tid & 7;
    const u16* src = v + ((size_t)(b * Sx + jt * 32 + row)) * Dm + h * 64 + cc * 8;
    *(s16x8*)&L[row * 72 + cc * 8] = *(const s16x8*)src;
    __syncthreads();
    int d = tid >> 2, jq = tid & 3;
    s16x8 o;
#pragma unroll
    for (int jj = 0; jj < 8; jj++) o[jj] = (short)L[(jq * 8 + jj) * 72 + d];
    u16* dst = vT + (((size_t)(b * 16 + h) * 64 + jt)) * 2048 + d * 32 + jq * 8;
    *(s16x8*)dst = o;
}

// ---------------------------------------------------------------- precompute u.k_j and vb.p_r (bf16 in)
__global__ __launch_bounds__(256) void ukvb_kernel(const u16* __restrict__ k,
                                                   const u16* __restrict__ pp,
                                                   const float* __restrict__ u,
                                                   const float* __restrict__ vb,
                                                   float* __restrict__ ukg,
                                                   float* __restrict__ vbg) {
    int jid = blockIdx.x * 256 + threadIdx.x;
    const u16* src; const float* vec; float* dst; int idx;
    if (jid < 2 * Hh * Sx) {
        int j = jid & 2047, h = (jid >> 11) & 15, b = jid >> 15;
        src = k + ((size_t)(b * Sx + j)) * Dm + h * 64;
        vec = u + h * 64; dst = ukg; idx = jid;
    } else {
        int j2 = jid - 2 * Hh * Sx;
        int r = j2 & 2047, h = j2 >> 11;
        src = pp + (size_t)r * Dm + h * 64;
        vec = vb + h * 64; dst = vbg; idx = j2;
    }
    float s = 0.0f;
#pragma unroll
    for (int c = 0; c < 8; c++) {
        s16x8 kk = *(const s16x8*)(src + c * 8);
#pragma unroll
        for (int i = 0; i < 8; i++) s += bf2f((u16)kk[i]) * vec[c * 8 + i];
    }
    dst[idx] = s;
}

// ---------------------------------------------------------------- MFMA helpers for flash
__device__ __forceinline__ void wfill2(const u16* Qs, const u16* PW,
                                       int qrow0, int g, int l15, f32x4& d0, f32x4& d1) {
    f32x4 z = {0.f, 0.f, 0.f, 0.f};
    s16x8 a0 = *(const s16x8*)&Qs[(qrow0 + l15) * 72 + g * 8];
    s16x8 a1 = *(const s16x8*)&Qs[(qrow0 + l15) * 72 + 32 + g * 8];
    s16x8 b00 = *(const s16x8*)&PW[l15 * 72 + g * 8];
    s16x8 b01 = *(const s16x8*)&PW[l15 * 72 + 32 + g * 8];
    s16x8 b10 = *(const s16x8*)&PW[(16 + l15) * 72 + g * 8];
    s16x8 b11 = *(const s16x8*)&PW[(16 + l15) * 72 + 32 + g * 8];
    d0 = __builtin_amdgcn_mfma_f32_16x16x32_bf16(a0, b00, z, 0, 0, 0);
    d0 = __builtin_amdgcn_mfma_f32_16x16x32_bf16(a1, b01, d0, 0, 0, 0);
    d1 = __builtin_amdgcn_mfma_f32_16x16x32_bf16(a0, b10, z, 0, 0, 0);
    d1 = __builtin_amdgcn_mfma_f32_16x16x32_bf16(a1, b11, d1, 0, 0, 0);
}

__device__ __forceinline__ void window_fill(const u16* Qs, const u16* PW, float* Ws,
                                            const float* __restrict__ vbb,
                                            int vstart, int sb, int w, int g, int l15) {
    f32x4 e0, e1;
    if (vstart + 31 <= Sx) {
        wfill2(Qs, PW, 16 * w, g, l15, e0, e1);
    } else if (vstart > Sx) {
        wfill2(Qs, PW, 16 * w + 1, g, l15, e0, e1);
    } else {
        f32x4 d0, d1, f0, f1;
        wfill2(Qs, PW, 16 * w,     g, l15, d0, d1);
        wfill2(Qs, PW, 16 * w + 1, g, l15, f0, f1);
        int v0 = vstart + l15, v1 = vstart + 16 + l15;
#pragma unroll
        for (int r = 0; r < 4; r++) {
            e0[r] = (v0 > Sx) ? f0[r] : d0[r];
            e1[r] = (v1 > Sx) ? f1[r] : d1[r];
        }
    }
    int v0 = vstart + l15, v1 = vstart + 16 + l15;
    int pc0 = v0 < Sx ? v0 : v0 - Sx - 1;
    int pc1 = v1 < Sx ? v1 : v1 - Sx - 1;
    float vb0 = (v0 == Sx) ? 0.0f : vbb[pc0];
    float vb1 = (v1 == Sx) ? 0.0f : vbb[pc1];
    int sl0 = sb + l15, sl1 = sb + 16 + l15;   // sb in {0,32,64}: no wrap needed
    int rbase = 16 * w + 4 * g;
#pragma unroll
    for (int r = 0; r < 4; r++) {
        Ws[(rbase + r) * 98 + sl0] = (v0 == Sx) ? 0.0f : e0[r] + vb0;
        Ws[(rbase + r) * 98 + sl1] = (v1 == Sx) ? 0.0f : e1[r] + vb1;
    }
}

// ---------------------------------------------------------------- flash attention (all-bf16 staging)
__global__ __launch_bounds__(256, 3) void flash_kernel(const u16* __restrict__ q,
                                                       const u16* __restrict__ k,
                                                       const u16* __restrict__ vt,
                                                       const u16* __restrict__ pp,
                                                       const float* __restrict__ ukg,
                                                       const float* __restrict__ vbg,
                                                       u16* __restrict__ head16) {
    __shared__ u16 Qs[65 * 72];
    __shared__ u16 Kt[32 * 72];
    __shared__ u16 PW[32 * 72];
    __shared__ u16 VT2[64 * 32];
    __shared__ u16 PA[64 * 40];
    __shared__ float Ws[64 * 98];

    int tid = threadIdx.x, blk = blockIdx.x;
    int it = blk & 31, h = (blk >> 5) & 15, b = blk >> 9;
    int i0 = it * 64;
    int a0 = 1984 - i0;

    const u16* qb  = q  + ((size_t)b * Sx) * Dm + h * 64;
    const u16* kb  = k  + ((size_t)b * Sx) * Dm + h * 64;
    const u16* vtb = vt + ((size_t)(b * 16 + h) * 64) * 2048;
    const u16* ppb = pp + h * 64;
    const float* ukb = ukg + (size_t)(b * Hh + h) * Sx;
    const float* vbb = vbg + (size_t)h * Sx;

    int w = tid >> 6, ln = tid & 63, g = ln >> 4, l15 = ln & 15;
    int rv = tid >> 3, ch = tid & 7;

    // stage Q (65 bf16 rows)
    for (int c = tid; c < 65 * 8; c += 256) {
        int row = c >> 3, cc = c & 7;
        int i = i0 + row;
        s16x8 tv = {0, 0, 0, 0, 0, 0, 0, 0};
        if (i < Sx) tv = *(const s16x8*)(qb + (size_t)i * Dm + cc * 8);
        *(s16x8*)&Qs[row * 72 + cc * 8] = tv;
    }

    // prologue window fills (vrb = 0, 32, 64)
    for (int f = 0; f < 3; f++) {
        int vrb = f * 32;
        __syncthreads();
        {
            int vv = a0 + vrb + rv;
            s16x8 tv = {0, 0, 0, 0, 0, 0, 0, 0};
            if (vv != Sx) {
                int pc = vv < Sx ? vv : vv - Sx - 1;
                tv = *(const s16x8*)(ppb + (size_t)pc * Dm + ch * 8);
            }
            *(s16x8*)&PW[rv * 72 + ch * 8] = tv;
        }
        __syncthreads();
        window_fill(Qs, PW, Ws, vbb, a0 + vrb, vrb, w, g, l15);
    }

    f32x4 O[4] = {{0.f,0.f,0.f,0.f},{0.f,0.f,0.f,0.f},{0.f,0.f,0.f,0.f},{0.f,0.f,0.f,0.f}};
    float m_i[4] = {-1e30f, -1e30f, -1e30f, -1e30f};
    float l_i[4] = {0.f, 0.f, 0.f, 0.f};
    int rbase = 16 * w + 4 * g;
    int sb = 0;                       // fill slot base (t>=1 fills)
    int srb = 63 - rbase;             // softmax slot base for this thread's rows
    const float SC = 0.125f * 1.44269504088896f;

    // preload tile 0
    s16x8 rK = *(const s16x8*)(kb + (size_t)rv * Dm + ch * 8);
    s16x8 rV = *(const s16x8*)(vtb + tid * 8);
    s16x8 rPW = {0, 0, 0, 0, 0, 0, 0, 0};

    for (int t = 0; t < 64; t++) {
        int j0 = t * 32;
        __syncthreads();   // B0: prior consumers done
        *(s16x8*)&Kt[rv * 72 + ch * 8] = rK;
        *(s16x8*)&VT2[tid * 8] = rV;
        if (t >= 1) *(s16x8*)&PW[rv * 72 + ch * 8] = rPW;
        {   // prefetch next tile (latency hidden across compute)
            int tn = (t + 1) & 63;
            rK = *(const s16x8*)(kb + (size_t)(tn * 32 + rv) * Dm + ch * 8);
            rV = *(const s16x8*)(vtb + (size_t)tn * 2048 + tid * 8);
            int vv = a0 + (t + 3) * 32 + rv;
            s16x8 z8 = {0, 0, 0, 0, 0, 0, 0, 0};
            if (vv != Sx) {
                int pc = vv < Sx ? vv : vv - Sx - 1;
                if (pc > Sx - 1) pc = Sx - 1;
                z8 = *(const s16x8*)(ppb + (size_t)pc * Dm + ch * 8);
            }
            rPW = z8;
        }
        float uk0 = ukb[j0 + l15];
        float uk1 = ukb[j0 + 16 + l15];
        __syncthreads();   // B1: tiles staged

        // content scores
        f32x4 s0, s1;
        {
            f32x4 z = {0.f, 0.f, 0.f, 0.f};
            s16x8 aq0 = *(const s16x8*)&Qs[(16 * w + l15) * 72 + g * 8];
            s16x8 aq1 = *(const s16x8*)&Qs[(16 * w + l15) * 72 + 32 + g * 8];
            s16x8 bk00 = *(const s16x8*)&Kt[l15 * 72 + g * 8];
            s16x8 bk01 = *(const s16x8*)&Kt[l15 * 72 + 32 + g * 8];
            s16x8 bk10 = *(const s16x8*)&Kt[(16 + l15) * 72 + g * 8];
            s16x8 bk11 = *(const s16x8*)&Kt[(16 + l15) * 72 + 32 + g * 8];
            s0 = __builtin_amdgcn_mfma_f32_16x16x32_bf16(aq0, bk00, z, 0, 0, 0);
            s0 = __builtin_amdgcn_mfma_f32_16x16x32_bf16(aq1, bk01, s0, 0, 0, 0);
            s1 = __builtin_amdgcn_mfma_f32_16x16x32_bf16(aq0, bk10, z, 0, 0, 0);
            s1 = __builtin_amdgcn_mfma_f32_16x16x32_bf16(aq1, bk11, s1, 0, 0, 0);
        }

        // window fill for vr in [j0+64, j0+96)
        if (t >= 1) {
            window_fill(Qs, PW, Ws, vbb, a0 + j0 + 64, sb, w, g, l15);
            sb += 32; if (sb >= 96) sb -= 96;
        }

        // combine + online softmax (deferred l-sum: per-lane partial)
        float p0v[4], p1v[4], alpha[4];
#pragma unroll
        for (int r = 0; r < 4; r++) {
            int row = rbase + r;
            int bb = srb - r; if (bb < 0) bb += 96;
            int si0 = bb + l15; if (si0 >= 96) si0 -= 96;
            int si1 = si0 + 16; if (si1 >= 96) si1 -= 96;
            float pos0 = Ws[row * 98 + si0];
            float pos1 = Ws[row * 98 + si1];
            float lg0 = (s0[r] + uk0 + pos0) * SC;
            float lg1 = (s1[r] + uk1 + pos1) * SC;
            float mx = fmaxf(lg0, lg1);
#pragma unroll
            for (int o = 1; o < 16; o <<= 1) mx = fmaxf(mx, __shfl_xor(mx, o, 64));
            float mn = fmaxf(m_i[r], mx);
            alpha[r] = exp2f(m_i[r] - mn);
            float e0 = exp2f(lg0 - mn), e1 = exp2f(lg1 - mn);
            l_i[r] = l_i[r] * alpha[r] + (e0 + e1);
            m_i[r] = mn;
            p0v[r] = e0; p1v[r] = e1;
        }
        srb += 32; if (srb >= 96) srb -= 96;
#pragma unroll
        for (int r = 0; r < 4; r++) {
            PA[(rbase + r) * 40 + l15]      = f2bf(p0v[r]);
            PA[(rbase + r) * 40 + 16 + l15] = f2bf(p1v[r]);
        }
#pragma unroll
        for (int nt = 0; nt < 4; nt++)
#pragma unroll
            for (int r = 0; r < 4; r++) O[nt][r] *= alpha[r];

        // O += P.V
        {
            s16x8 ap = *(const s16x8*)&PA[(16 * w + l15) * 40 + g * 8];
#pragma unroll
            for (int nt = 0; nt < 4; nt++) {
                s16x8 bv = *(const s16x8*)&VT2[(nt * 16 + l15) * 32 + g * 8];
                O[nt] = __builtin_amdgcn_mfma_f32_16x16x32_bf16(ap, bv, O[nt], 0, 0, 0);
            }
        }
    }

    // epilogue: cross-lane l sum, write pre-split bf16 head
#pragma unroll
    for (int r = 0; r < 4; r++) {
        float l = l_i[r];
#pragma unroll
        for (int o = 1; o < 16; o <<= 1) l += __shfl_xor(l, o, 64);
        float inv = 1.0f / l;
        int grow = i0 + rbase + r;
        u16* dst = head16 + (size_t)(b * Sx + grow) * 2048 + h * 64 + l15;
#pragma unroll
        for (int nt = 0; nt < 4; nt++) {
            float f = O[nt][r] * inv;
            u16 hh = f2bf(f);
            dst[16 * nt]        = hh;
            dst[1024 + 16 * nt] = f2bf(f - bf2f(hh));
        }
    }
}

// ---------------------------------------------------------------- launcher
extern "C" void kernel_launch(void* const* d_in, const int* in_sizes, int n_in,
                              void* d_out, int out_size, void* d_ws, size_t ws_size,
                              hipStream_t stream) {
    const float* x    = (const float*)d_in[0];
    const float* ln_g = (const float*)d_in[1];
    const float* ln_b = (const float*)d_in[2];
    const float* Wq   = (const float*)d_in[3];
    const float* bq   = (const float*)d_in[4];
    const float* Wk   = (const float*)d_in[5];
    const float* bk   = (const float*)d_in[6];
    const float* Wv   = (const float*)d_in[7];
    const float* bv   = (const float*)d_in[8];
    const float* Wp   = (const float*)d_in[9];
    const float* Wo   = (const float*)d_in[10];
    const float* bo   = (const float*)d_in[11];
    const float* ub   = (const float*)d_in[12];
    const float* vbias= (const float*)d_in[13];

    float* out = (float*)d_out;
    u16* base  = (u16*)d_ws;

    const int MROWS = 2 * Sx;                          // 4096
    u16* xn16   = base;                                // [4096][2048] hi|lo
    u16* head16 = base + 8u  * 1024 * 1024;            // [4096][2048] hi|lo
    u16* pe16   = base + 16u * 1024 * 1024;            // [2048][2048] hi|lo
    u16* qb16   = base + 20u * 1024 * 1024;            // [4096][1024]
    u16* kb16   = base + 24u * 1024 * 1024;
    u16* vb16   = base + 28u * 1024 * 1024;
    u16* pp16   = base + 32u * 1024 * 1024;            // [2048][1024]
    u16* vT16   = base + 34u * 1024 * 1024;            // [2][16][64][64][32]
    u16* WT     = base + 38u * 1024 * 1024;            // 5 x [1024][2048]
    float* ukg  = (float*)(base + 48u * 1024 * 1024);  // [2*16*2048]
    float* vbg  = ukg + 2 * Hh * Sx;                   // [16*2048]

    ln_kernel<<<MROWS, 256, 0, stream>>>(x, ln_g, ln_b, xn16);
    pe_kernel<<<Sx * 512 / 256, 256, 0, stream>>>(pe16);

    dim3 gw(32, 32, 5);
    wconv_kernel<<<gw, 256, 0, stream>>>(Wq, Wk, Wv, Wp, Wo, WT);

    dim3 g1(8, MROWS / 64);
    dim3 g2(8, Sx / 64);
    gemm_bf16x3<<<g1, 256, 0, stream>>>(xn16, WT + 0u * 1024 * 2048, bq, nullptr, qb16, MROWS);
    gemm_bf16x3<<<g1, 256, 0, stream>>>(xn16, WT + 1u * 1024 * 2048, bk, nullptr, kb16, MROWS);
    gemm_bf16x3<<<g1, 256, 0, stream>>>(xn16, WT + 2u * 1024 * 2048, bv, nullptr, vb16, MROWS);
    gemm_bf16x3<<<g2, 256, 0, stream>>>(pe16, WT + 3u * 1024 * 2048, nullptr, nullptr, pp16, Sx);

    dim3 gv(Sx / 32, Hh, 2);
    vtrans_kernel<<<gv, 256, 0, stream>>>(vb16, vT16);

    ukvb_kernel<<<(2 * Hh * Sx + Hh * Sx) / 256, 256, 0, stream>>>(kb16, pp16, ub, vbias, ukg, vbg);

    flash_kernel<<<2 * Hh * 32, 256, 0, stream>>>(qb16, kb16, vT16, pp16, ukg, vbg, head16);

    gemm_bf16x3<<<g1, 256, 0, stream>>>(head16, WT + 4u * 1024 * 2048, bo, out, nullptr, MROWS);
}

// Round 7
// 518.344 us; speedup vs baseline: 34.1966x; 1.0742x over previous
//
#include <hip/hip_runtime.h>
#include <hip/hip_bf16.h>
#include <math.h>

#define Dm   1024
#define Hh   16
#define Sx   2048

typedef short s16x8 __attribute__((ext_vector_type(8)));
typedef float f32x4 __attribute__((ext_vector_type(4)));
typedef unsigned short u16;
typedef u16 u16x4 __attribute__((ext_vector_type(4)));

#if defined(__has_builtin)
#  if __has_builtin(__builtin_amdgcn_cvt_pk_bf16_f32)
#    define HAVE_PKBF16 1
typedef __bf16 bfv2 __attribute__((ext_vector_type(2)));
#  endif
#  if __has_builtin(__builtin_amdgcn_exp2f)
#    define EXP2(x) __builtin_amdgcn_exp2f(x)
#  endif
#endif
#ifndef EXP2
#  define EXP2(x) exp2f(x)
#endif

// logit scale folded into k and p: dh^-0.5 * log2(e)
#define ATT_SCALE 0.1803368801111204f

__device__ __forceinline__ float wave_sum64(float v) {
#pragma unroll
    for (int o = 32; o > 0; o >>= 1) v += __shfl_xor(v, o, 64);
    return v;
}
__device__ __forceinline__ u16 f2bf(float x) {
    unsigned int u = __float_as_uint(x);
    unsigned int r = u + 0x7FFFu + ((u >> 16) & 1u);
    return (u16)(r >> 16);
}
__device__ __forceinline__ float bf2f(u16 h) {
    return __uint_as_float(((unsigned int)h) << 16);
}

// ---------------------------------------------------------------- LayerNorm -> pre-split bf16 hi|lo
__global__ __launch_bounds__(256) void ln_kernel(const float* __restrict__ x,
                                                 const float* __restrict__ g,
                                                 const float* __restrict__ b,
                                                 u16* __restrict__ out16) {
    int row = blockIdx.x;
    int tid = threadIdx.x;
    const float4* xr = (const float4*)(x + (size_t)row * Dm);
    float4 v = xr[tid];
    float s  = v.x + v.y + v.z + v.w;
    float ss = v.x * v.x + v.y * v.y + v.z * v.z + v.w * v.w;
    __shared__ float rbuf[8];
    s  = wave_sum64(s);
    ss = wave_sum64(ss);
    if ((tid & 63) == 0) { rbuf[tid >> 6] = s; rbuf[4 + (tid >> 6)] = ss; }
    __syncthreads();
    float mean = (rbuf[0] + rbuf[1] + rbuf[2] + rbuf[3]) * (1.0f / Dm);
    float msq  = (rbuf[4] + rbuf[5] + rbuf[6] + rbuf[7]) * (1.0f / Dm);
    float var  = msq - mean * mean;
    float rstd = 1.0f / sqrtf(var + 1e-5f);
    float4 gg = ((const float4*)g)[tid];
    float4 bb = ((const float4*)b)[tid];
    float o[4];
    o[0] = (v.x - mean) * rstd * gg.x + bb.x;
    o[1] = (v.y - mean) * rstd * gg.y + bb.y;
    o[2] = (v.z - mean) * rstd * gg.z + bb.z;
    o[3] = (v.w - mean) * rstd * gg.w + bb.w;
    u16x4 hi, lo;
#pragma unroll
    for (int i = 0; i < 4; i++) {
        u16 h = f2bf(o[i]);
        hi[i] = h;
        lo[i] = f2bf(o[i] - bf2f(h));
    }
    *(u16x4*)&out16[(size_t)row * 2048 + tid * 4]        = hi;
    *(u16x4*)&out16[(size_t)row * 2048 + 1024 + tid * 4] = lo;
}

// ---------------------------------------------------------------- sinusoidal PE -> pre-split bf16
__global__ __launch_bounds__(256) void pe_kernel(u16* __restrict__ pe16) {
    int idx = blockIdx.x * 256 + threadIdx.x;
    int r = idx >> 9;
    int t = idx & 511;
    double div = exp((double)(2 * t) * (-9.210340371976184 / 1024.0));
    double ang = (double)r * div;
    float sv = (float)sin(ang), cv = (float)cos(ang);
    u16 sh = f2bf(sv), chh = f2bf(cv);
    u16* row = pe16 + (size_t)r * 2048;
    row[2 * t]            = sh;
    row[2 * t + 1]        = chh;
    row[1024 + 2 * t]     = f2bf(sv - bf2f(sh));
    row[1024 + 2 * t + 1] = f2bf(cv - bf2f(chh));
}

// ---------------------------------------------------------------- weight transpose + bf16 hi/lo split
__global__ __launch_bounds__(256) void wconv_kernel(const float* __restrict__ W0,
                                                    const float* __restrict__ W1,
                                                    const float* __restrict__ W2,
                                                    const float* __restrict__ W3,
                                                    const float* __restrict__ W4,
                                                    u16* __restrict__ WT) {
    int wz = blockIdx.z;
    const float* W = (wz == 0) ? W0 : (wz == 1) ? W1 : (wz == 2) ? W2 : (wz == 3) ? W3 : W4;
    u16* T = WT + (size_t)wz * 1024 * 2048;
    __shared__ float tile[32][33];
    int n0 = blockIdx.x * 32, k0 = blockIdx.y * 32;
    int tx = threadIdx.x & 31, ty = threadIdx.x >> 5;
#pragma unroll
    for (int r = 0; r < 32; r += 8)
        tile[ty + r][tx] = W[(size_t)(k0 + ty + r) * 1024 + n0 + tx];
    __syncthreads();
#pragma unroll
    for (int r = 0; r < 32; r += 8) {
        int n = ty + r;
        float x = tile[tx][n];
        u16 h = f2bf(x);
        float rem = x - bf2f(h);
        T[(size_t)(n0 + n) * 2048 + k0 + tx]        = h;
        T[(size_t)(n0 + n) * 2048 + 1024 + k0 + tx] = f2bf(rem);
    }
}

// ---------------------------------------------------------------- bf16x3 MFMA GEMM (pre-split A and B)
// C = (A @ W + bias) * cscale
__global__ __launch_bounds__(256, 4) void gemm_bf16x3(const u16* __restrict__ A16,
                                                      const u16* __restrict__ WT,
                                                      const float* __restrict__ bias,
                                                      float cscale,
                                                      float* __restrict__ C,
                                                      u16* __restrict__ Cb, int M) {
    const int K = 1024, N = 1024;
    __shared__ __align__(16) u16 Ah[64 * 72];
    __shared__ __align__(16) u16 Bh[128 * 72];
    int tid = threadIdx.x;
    int bn = blockIdx.x * 128, bm = blockIdx.y * 64;
    int ar = tid >> 2, ac = (tid & 3) * 8;
    int br = tid >> 1, bs = (tid & 1);
    int w = tid >> 6, ln = tid & 63, g = ln >> 4, l15 = ln & 15;
    int wm = (w & 1) * 32, wn = (w >> 1) * 64;

    const u16* Ap = A16 + (size_t)(bm + ar) * 2048 + ac;
    const u16* Bp = WT + (size_t)(bn + br) * 2048 + bs * 1024;
    u16* Aw = &Ah[ar * 72 + ac];
    u16* Bw = &Bh[br * 72 + bs * 32];

    f32x4 acc[2][4] = {};
    s16x8 pah = *(const s16x8*)Ap;
    s16x8 pal = *(const s16x8*)(Ap + 1024);
    s16x8 pb0 = *(const s16x8*)Bp;
    s16x8 pb1 = *(const s16x8*)(Bp + 8);
    s16x8 pb2 = *(const s16x8*)(Bp + 16);
    s16x8 pb3 = *(const s16x8*)(Bp + 24);

    for (int k0 = 0; k0 < K; k0 += 32) {
        __syncthreads();
        *(s16x8*)Aw        = pah;
        *(s16x8*)(Aw + 32) = pal;
        *(s16x8*)Bw        = pb0;
        *(s16x8*)(Bw + 8)  = pb1;
        *(s16x8*)(Bw + 16) = pb2;
        *(s16x8*)(Bw + 24) = pb3;
        int kn = k0 + 32;
        if (kn < K) {
            pah = *(const s16x8*)(Ap + kn);
            pal = *(const s16x8*)(Ap + 1024 + kn);
            pb0 = *(const s16x8*)(Bp + kn);
            pb1 = *(const s16x8*)(Bp + kn + 8);
            pb2 = *(const s16x8*)(Bp + kn + 16);
            pb3 = *(const s16x8*)(Bp + kn + 24);
        }
        __syncthreads();
        s16x8 ah0 = *(const s16x8*)&Ah[(wm + l15) * 72 + g * 8];
        s16x8 al0 = *(const s16x8*)&Ah[(wm + l15) * 72 + 32 + g * 8];
        s16x8 ah1 = *(const s16x8*)&Ah[(wm + 16 + l15) * 72 + g * 8];
        s16x8 al1 = *(const s16x8*)&Ah[(wm + 16 + l15) * 72 + 32 + g * 8];
#pragma unroll
        for (int nt = 0; nt < 4; nt++) {
            int n = (wn + 16 * nt + l15) * 72;
            s16x8 bh = *(const s16x8*)&Bh[n + g * 8];
            s16x8 bl = *(const s16x8*)&Bh[n + 32 + g * 8];
            acc[0][nt] = __builtin_amdgcn_mfma_f32_16x16x32_bf16(ah0, bh, acc[0][nt], 0, 0, 0);
            acc[0][nt] = __builtin_amdgcn_mfma_f32_16x16x32_bf16(al0, bh, acc[0][nt], 0, 0, 0);
            acc[0][nt] = __builtin_amdgcn_mfma_f32_16x16x32_bf16(ah0, bl, acc[0][nt], 0, 0, 0);
            acc[1][nt] = __builtin_amdgcn_mfma_f32_16x16x32_bf16(ah1, bh, acc[1][nt], 0, 0, 0);
            acc[1][nt] = __builtin_amdgcn_mfma_f32_16x16x32_bf16(al1, bh, acc[1][nt], 0, 0, 0);
            acc[1][nt] = __builtin_amdgcn_mfma_f32_16x16x32_bf16(ah1, bl, acc[1][nt], 0, 0, 0);
        }
    }

    float bv[4];
#pragma unroll
    for (int nt = 0; nt < 4; nt++)
        bv[nt] = bias ? bias[bn + wn + 16 * nt + l15] : 0.0f;
#pragma unroll
    for (int mt = 0; mt < 2; mt++)
#pragma unroll
        for (int r = 0; r < 4; r++) {
            int row = bm + wm + 16 * mt + g * 4 + r;
            if (Cb) {
                u16* cp = Cb + (size_t)row * N + bn + wn + l15;
#pragma unroll
                for (int nt = 0; nt < 4; nt++)
                    cp[16 * nt] = f2bf((acc[mt][nt][r] + bv[nt]) * cscale);
            } else {
                float* cp = C + (size_t)row * N + bn + wn + l15;
#pragma unroll
                for (int nt = 0; nt < 4; nt++)
                    cp[16 * nt] = (acc[mt][nt][r] + bv[nt]) * cscale;
            }
        }
}

// ---------------------------------------------------------------- V transpose to tiled [b][h][jt][d][32]
__global__ __launch_bounds__(256) void vtrans_kernel(const u16* __restrict__ v,
                                                     u16* __restrict__ vT) {
    __shared__ u16 L[32 * 72];
    int jt = blockIdx.x, h = blockIdx.y, b = blockIdx.z;
    int tid = threadIdx.x;
    int row = tid >> 3, cc = tid & 7;
    const u16* src = v + ((size_t)(b * Sx + jt * 32 + row)) * Dm + h * 64 + cc * 8;
    *(s16x8*)&L[row * 72 + cc * 8] = *(const s16x8*)src;
    __syncthreads();
    int d = tid >> 2, jq = tid & 3;
    s16x8 o;
#pragma unroll
    for (int jj = 0; jj < 8; jj++) o[jj] = (short)L[(jq * 8 + jj) * 72 + d];
    u16* dst = vT + (((size_t)(b * 16 + h) * 64 + jt)) * 2048 + d * 32 + jq * 8;
    *(s16x8*)dst = o;
}

// ---------------------------------------------------------------- precompute u.k_j and vb.p_r (bf16 in; k/p pre-scaled)
__global__ __launch_bounds__(256) void ukvb_kernel(const u16* __restrict__ k,
                                                   const u16* __restrict__ pp,
                                                   const float* __restrict__ u,
                                                   const float* __restrict__ vb,
                                                   float* __restrict__ ukg,
                                                   float* __restrict__ vbg) {
    int jid = blockIdx.x * 256 + threadIdx.x;
    const u16* src; const float* vec; float* dst; int idx;
    if (jid < 2 * Hh * Sx) {
        int j = jid & 2047, h = (jid >> 11) & 15, b = jid >> 15;
        src = k + ((size_t)(b * Sx + j)) * Dm + h * 64;
        vec = u + h * 64; dst = ukg; idx = jid;
    } else {
        int j2 = jid - 2 * Hh * Sx;
        int r = j2 & 2047, h = j2 >> 11;
        src = pp + (size_t)r * Dm + h * 64;
        vec = vb + h * 64; dst = vbg; idx = j2;
    }
    float s = 0.0f;
#pragma unroll
    for (int c = 0; c < 8; c++) {
        s16x8 kk = *(const s16x8*)(src + c * 8);
#pragma unroll
        for (int i = 0; i < 8; i++) s += bf2f((u16)kk[i]) * vec[c * 8 + i];
    }
    dst[idx] = s;
}

// ---------------------------------------------------------------- MFMA helpers for flash
__device__ __forceinline__ void wfill2(s16x8 a0, s16x8 a1, const u16* PW,
                                       int g, int l15, f32x4& d0, f32x4& d1) {
    f32x4 z = {0.f, 0.f, 0.f, 0.f};
    s16x8 b00 = *(const s16x8*)&PW[l15 * 72 + g * 8];
    s16x8 b01 = *(const s16x8*)&PW[l15 * 72 + 32 + g * 8];
    s16x8 b10 = *(const s16x8*)&PW[(16 + l15) * 72 + g * 8];
    s16x8 b11 = *(const s16x8*)&PW[(16 + l15) * 72 + 32 + g * 8];
    d0 = __builtin_amdgcn_mfma_f32_16x16x32_bf16(a0, b00, z, 0, 0, 0);
    d0 = __builtin_amdgcn_mfma_f32_16x16x32_bf16(a1, b01, d0, 0, 0, 0);
    d1 = __builtin_amdgcn_mfma_f32_16x16x32_bf16(a0, b10, z, 0, 0, 0);
    d1 = __builtin_amdgcn_mfma_f32_16x16x32_bf16(a1, b11, d1, 0, 0, 0);
}

// fill window chunk: skewed circular slots, physical = (logical_vr + row) % 96, stride 98
__device__ __forceinline__ void window_fill(s16x8 aq0, s16x8 aq1, s16x8 ab0, s16x8 ab1,
                                            const u16* PW, float* Ws,
                                            const float* __restrict__ vbb,
                                            int vstart, int sb, int rbase, int g, int l15) {
    f32x4 e0, e1;
    if (vstart + 31 <= Sx) {
        wfill2(aq0, aq1, PW, g, l15, e0, e1);
    } else if (vstart > Sx) {
        wfill2(ab0, ab1, PW, g, l15, e0, e1);
    } else {
        f32x4 d0, d1, f0, f1;
        wfill2(aq0, aq1, PW, g, l15, d0, d1);
        wfill2(ab0, ab1, PW, g, l15, f0, f1);
        int v0 = vstart + l15, v1 = vstart + 16 + l15;
#pragma unroll
        for (int r = 0; r < 4; r++) {
            e0[r] = (v0 > Sx) ? f0[r] : d0[r];
            e1[r] = (v1 > Sx) ? f1[r] : d1[r];
        }
    }
    int v0 = vstart + l15, v1 = vstart + 16 + l15;
    int pc0 = v0 < Sx ? v0 : v0 - Sx - 1;
    int pc1 = v1 < Sx ? v1 : v1 - Sx - 1;
    float vb0 = (v0 == Sx) ? 0.0f : vbb[pc0];
    float vb1 = (v1 == Sx) ? 0.0f : vbb[pc1];
    int bs = sb + rbase;
#pragma unroll
    for (int r = 0; r < 4; r++) {
        int b2 = bs + r; if (b2 >= 96) b2 -= 96;
        int sl0 = b2 + l15; if (sl0 >= 96) sl0 -= 96;
        int sl1 = sl0 + 16; if (sl1 >= 96) sl1 -= 96;
        Ws[(rbase + r) * 98 + sl0] = (v0 == Sx) ? 0.0f : e0[r] + vb0;
        Ws[(rbase + r) * 98 + sl1] = (v1 == Sx) ? 0.0f : e1[r] + vb1;
    }
}

// ---------------------------------------------------------------- flash attention
// wave-shared softmax max (any upper bound is exact math), skewed window slots,
// hoisted Q fragments, incremental prefetch, PA column swizzle.
__global__ __launch_bounds__(256, 3) void flash_kernel(const u16* __restrict__ q,
                                                       const u16* __restrict__ k,
                                                       const u16* __restrict__ vt,
                                                       const u16* __restrict__ pp,
                                                       const float* __restrict__ ukg,
                                                       const float* __restrict__ vbg,
                                                       u16* __restrict__ head16) {
    __shared__ u16 Qs[65 * 72];
    __shared__ u16 Kt[32 * 72];
    __shared__ u16 PW[32 * 72];
    __shared__ u16 VT2[64 * 32];
    __shared__ u16 PA[64 * 40];
    __shared__ float Ws[64 * 98];

    int tid = threadIdx.x, blk = blockIdx.x;
    int it = blk & 31, h = (blk >> 5) & 15, b = blk >> 9;
    int i0 = it * 64;
    int a0 = 1984 - i0;

    const u16* qb  = q  + ((size_t)b * Sx) * Dm + h * 64;
    const u16* kb  = k  + ((size_t)b * Sx) * Dm + h * 64;
    const u16* vtb = vt + ((size_t)(b * 16 + h) * 64) * 2048;
    const u16* ppb = pp + h * 64;
    const float* ukb = ukg + (size_t)(b * Hh + h) * Sx;
    const float* vbb = vbg + (size_t)h * Sx;

    int w = tid >> 6, ln = tid & 63, g = ln >> 4, l15 = ln & 15;
    int rv = tid >> 3, ch = tid & 7;
    int rbase = 16 * w + 4 * g;

    // stage Q (65 bf16 rows)
    for (int c = tid; c < 65 * 8; c += 256) {
        int row = c >> 3, cc = c & 7;
        int i = i0 + row;
        s16x8 tv = {0, 0, 0, 0, 0, 0, 0, 0};
        if (i < Sx) tv = *(const s16x8*)(qb + (size_t)i * Dm + cc * 8);
        *(s16x8*)&Qs[row * 72 + cc * 8] = tv;
    }
    __syncthreads();

    // hoisted, loop-invariant A fragments (QK row and row+1 for window fill)
    s16x8 aq0 = *(const s16x8*)&Qs[(16 * w + l15) * 72 + g * 8];
    s16x8 aq1 = *(const s16x8*)&Qs[(16 * w + l15) * 72 + 32 + g * 8];
    s16x8 ab0 = *(const s16x8*)&Qs[(16 * w + 1 + l15) * 72 + g * 8];
    s16x8 ab1 = *(const s16x8*)&Qs[(16 * w + 1 + l15) * 72 + 32 + g * 8];

    // prologue window fills: logical vrb = 0, 32, 64
    for (int f = 0; f < 3; f++) {
        int vrb = f * 32;
        if (f) __syncthreads();
        {
            int vv = a0 + vrb + rv;
            s16x8 tv = {0, 0, 0, 0, 0, 0, 0, 0};
            if (vv != Sx) {
                int pc = vv < Sx ? vv : vv - Sx - 1;
                tv = *(const s16x8*)(ppb + (size_t)pc * Dm + ch * 8);
            }
            *(s16x8*)&PW[rv * 72 + ch * 8] = tv;
        }
        __syncthreads();
        window_fill(aq0, aq1, ab0, ab1, PW, Ws, vbb, a0 + vrb, vrb, rbase, g, l15);
    }

    f32x4 O[4] = {{0.f,0.f,0.f,0.f},{0.f,0.f,0.f,0.f},{0.f,0.f,0.f,0.f},{0.f,0.f,0.f,0.f}};
    float m_w = -1e30f;
    float l_i[4] = {0.f, 0.f, 0.f, 0.f};
    int wro[4];
#pragma unroll
    for (int r = 0; r < 4; r++) wro[r] = (rbase + r) * 98;
    int sb = 0;                 // fill slot base, cycles 0,32,64
    int jm = 63;                // (63 + j0) % 96
    int cw = (g >= 2) ? 16 : 0;           // PA write column swizzle
    int crd = (l15 >> 3) << 4;            // PA read column swizzle

    // incremental prefetch pointers (over-run at t=63 stays inside workspace)
    const u16* pK = kb + (size_t)rv * Dm + ch * 8;
    const u16* pV = vtb + tid * 8;
    s16x8 rK = *(const s16x8*)pK;
    s16x8 rV = *(const s16x8*)pV;
    s16x8 rPW = {0, 0, 0, 0, 0, 0, 0, 0};

    for (int t = 0; t < 64; t++) {
        int j0 = t * 32;
        __syncthreads();   // B0
        *(s16x8*)&Kt[rv * 72 + ch * 8] = rK;
        *(s16x8*)&VT2[tid * 8] = rV;
        if (t >= 1) *(s16x8*)&PW[rv * 72 + ch * 8] = rPW;
        pK += 32 * Dm;
        pV += 2048;
        rK = *(const s16x8*)pK;
        rV = *(const s16x8*)pV;
        {
            int vv = a0 + (t + 3) * 32 + rv;
            s16x8 z8 = {0, 0, 0, 0, 0, 0, 0, 0};
            if (vv != Sx) {
                int pc = vv < Sx ? vv : vv - Sx - 1;
                if (pc > Sx - 1) pc = Sx - 1;
                z8 = *(const s16x8*)(ppb + (size_t)pc * Dm + ch * 8);
            }
            rPW = z8;
        }
        float uk0 = ukb[j0 + l15];
        float uk1 = ukb[j0 + 16 + l15];
        __syncthreads();   // B1

        // ---- content scores (pre-scaled k)
        f32x4 s0, s1;
        {
            f32x4 z = {0.f, 0.f, 0.f, 0.f};
            s16x8 bk00 = *(const s16x8*)&Kt[l15 * 72 + g * 8];
            s16x8 bk01 = *(const s16x8*)&Kt[l15 * 72 + 32 + g * 8];
            s16x8 bk10 = *(const s16x8*)&Kt[(16 + l15) * 72 + g * 8];
            s16x8 bk11 = *(const s16x8*)&Kt[(16 + l15) * 72 + 32 + g * 8];
            s0 = __builtin_amdgcn_mfma_f32_16x16x32_bf16(aq0, bk00, z, 0, 0, 0);
            s0 = __builtin_amdgcn_mfma_f32_16x16x32_bf16(aq1, bk01, s0, 0, 0, 0);
            s1 = __builtin_amdgcn_mfma_f32_16x16x32_bf16(aq0, bk10, z, 0, 0, 0);
            s1 = __builtin_amdgcn_mfma_f32_16x16x32_bf16(aq1, bk11, s1, 0, 0, 0);
        }

        // ---- window fill for logical vr in [j0+64, j0+96)
        if (t >= 1) {
            window_fill(aq0, aq1, ab0, ab1, PW, Ws, vbb, a0 + j0 + 64, sb, rbase, g, l15);
            sb += 32; if (sb >= 96) sb -= 96;
        }

        // ---- combine + online softmax; skewed read slots are row-independent
        int si0 = jm + l15; if (si0 >= 96) si0 -= 96;
        int si1 = si0 + 16; if (si1 >= 96) si1 -= 96;
        jm += 32; if (jm >= 96) jm -= 96;
        float lg0[4], lg1[4];
#pragma unroll
        for (int r = 0; r < 4; r++) {
            lg0[r] = s0[r] + uk0 + Ws[wro[r] + si0];
            lg1[r] = s1[r] + uk1 + Ws[wro[r] + si1];
        }
        float mx = fmaxf(fmaxf(fmaxf(lg0[0], lg1[0]), fmaxf(lg0[1], lg1[1])),
                         fmaxf(fmaxf(lg0[2], lg1[2]), fmaxf(lg0[3], lg1[3])));
#pragma unroll
        for (int o = 1; o < 64; o <<= 1) mx = fmaxf(mx, __shfl_xor(mx, o, 64));
        if (mx > m_w) {                      // wave-uniform; rare after warmup
            float alpha = EXP2(m_w - mx);
            m_w = mx;
            l_i[0] *= alpha; l_i[1] *= alpha; l_i[2] *= alpha; l_i[3] *= alpha;
#pragma unroll
            for (int nt = 0; nt < 4; nt++)
#pragma unroll
                for (int r = 0; r < 4; r++) O[nt][r] *= alpha;
        }
        int c0 = l15 + cw;
        int c1 = l15 + 16 - cw;
#pragma unroll
        for (int r = 0; r < 4; r++) {
            float e0v = EXP2(lg0[r] - m_w);
            float e1v = EXP2(lg1[r] - m_w);
            l_i[r] += e0v + e1v;
#ifdef HAVE_PKBF16
            bfv2 pk2 = __builtin_amdgcn_cvt_pk_bf16_f32(e0v, e1v);
            PA[(rbase + r) * 40 + c0] = __builtin_bit_cast(u16, pk2[0]);
            PA[(rbase + r) * 40 + c1] = __builtin_bit_cast(u16, pk2[1]);
#else
            PA[(rbase + r) * 40 + c0] = f2bf(e0v);
            PA[(rbase + r) * 40 + c1] = f2bf(e1v);
#endif
        }

        // ---- O += P.V (swizzled A read)
        {
            s16x8 ap = *(const s16x8*)&PA[(16 * w + l15) * 40 + ((g * 8 + crd) & 31)];
#pragma unroll
            for (int nt = 0; nt < 4; nt++) {
                s16x8 bv = *(const s16x8*)&VT2[(nt * 16 + l15) * 32 + g * 8];
                O[nt] = __builtin_amdgcn_mfma_f32_16x16x32_bf16(ap, bv, O[nt], 0, 0, 0);
            }
        }
    }

    // epilogue: cross-lane l sum, write pre-split bf16 head
#pragma unroll
    for (int r = 0; r < 4; r++) {
        float l = l_i[r];
#pragma unroll
        for (int o = 1; o < 16; o <<= 1) l += __shfl_xor(l, o, 64);
        float inv = 1.0f / l;
        int grow = i0 + rbase + r;
        u16* dst = head16 + (size_t)(b * Sx + grow) * 2048 + h * 64 + l15;
#pragma unroll
        for (int nt = 0; nt < 4; nt++) {
            float f = O[nt][r] * inv;
            u16 hh = f2bf(f);
            dst[16 * nt]        = hh;
            dst[1024 + 16 * nt] = f2bf(f - bf2f(hh));
        }
    }
}

// ---------------------------------------------------------------- launcher
extern "C" void kernel_launch(void* const* d_in, const int* in_sizes, int n_in,
                              void* d_out, int out_size, void* d_ws, size_t ws_size,
                              hipStream_t stream) {
    const float* x    = (const float*)d_in[0];
    const float* ln_g = (const float*)d_in[1];
    const float* ln_b = (const float*)d_in[2];
    const float* Wq   = (const float*)d_in[3];
    const float* bq   = (const float*)d_in[4];
    const float* Wk   = (const float*)d_in[5];
    const float* bk   = (const float*)d_in[6];
    const float* Wv   = (const float*)d_in[7];
    const float* bv   = (const float*)d_in[8];
    const float* Wp   = (const float*)d_in[9];
    const float* Wo   = (const float*)d_in[10];
    const float* bo   = (const float*)d_in[11];
    const float* ub   = (const float*)d_in[12];
    const float* vbias= (const float*)d_in[13];

    float* out = (float*)d_out;
    u16* base  = (u16*)d_ws;

    const int MROWS = 2 * Sx;                          // 4096
    u16* xn16   = base;                                // [4096][2048] hi|lo
    u16* head16 = base + 8u  * 1024 * 1024;            // [4096][2048] hi|lo
    u16* pe16   = base + 16u * 1024 * 1024;            // [2048][2048] hi|lo
    u16* qb16   = base + 20u * 1024 * 1024;            // [4096][1024]
    u16* kb16   = base + 24u * 1024 * 1024;
    u16* vb16   = base + 28u * 1024 * 1024;
    u16* pp16   = base + 32u * 1024 * 1024;            // [2048][1024]
    u16* vT16   = base + 34u * 1024 * 1024;            // [2][16][64][64][32]
    u16* WT     = base + 38u * 1024 * 1024;            // 5 x [1024][2048]
    float* ukg  = (float*)(base + 48u * 1024 * 1024);
    float* vbg  = ukg + 2 * Hh * Sx;

    ln_kernel<<<MROWS, 256, 0, stream>>>(x, ln_g, ln_b, xn16);
    pe_kernel<<<Sx * 512 / 256, 256, 0, stream>>>(pe16);

    dim3 gw(32, 32, 5);
    wconv_kernel<<<gw, 256, 0, stream>>>(Wq, Wk, Wv, Wp, Wo, WT);

    dim3 g1(8, MROWS / 64);
    dim3 g2(8, Sx / 64);
    gemm_bf16x3<<<g1, 256, 0, stream>>>(xn16, WT + 0u * 1024 * 2048, bq, 1.0f,      nullptr, qb16, MROWS);
    gemm_bf16x3<<<g1, 256, 0, stream>>>(xn16, WT + 1u * 1024 * 2048, bk, ATT_SCALE, nullptr, kb16, MROWS);
    gemm_bf16x3<<<g1, 256, 0, stream>>>(xn16, WT + 2u * 1024 * 2048, bv, 1.0f,      nullptr, vb16, MROWS);
    gemm_bf16x3<<<g2, 256, 0, stream>>>(pe16, WT + 3u * 1024 * 2048, nullptr, ATT_SCALE, nullptr, pp16, Sx);

    dim3 gv(Sx / 32, Hh, 2);
    vtrans_kernel<<<gv, 256, 0, stream>>>(vb16, vT16);

    ukvb_kernel<<<(2 * Hh * Sx + Hh * Sx) / 256, 256, 0, stream>>>(kb16, pp16, ub, vbias, ukg, vbg);

    flash_kernel<<<2 * Hh * 32, 256, 0, stream>>>(qb16, kb16, vT16, pp16, ukg, vbg, head16);

    gemm_bf16x3<<<g1, 256, 0, stream>>>(head16, WT + 4u * 1024 * 2048, bo, 1.0f, out, nullptr, MROWS);
}